// Round 2
// baseline (1308.369 us; speedup 1.0000x reference)
//
#include <hip/hip_runtime.h>

// ---------- static device workspace (avoids unknown ws_size) ----------
static __device__ __align__(256) unsigned char g_ws[505413632];

// ---------- types ----------
typedef __attribute__((ext_vector_type(8))) __bf16 bf16x8;
typedef __attribute__((ext_vector_type(4))) float  f32x4;

__device__ __forceinline__ short f2bf(float f) {
    union { float f; unsigned u; } v; v.f = f;
    unsigned r = v.u + 0x7FFFu + ((v.u >> 16) & 1u);
    return (short)(r >> 16);
}
__device__ __forceinline__ float elu1(float x) {
    return x > 0.f ? x + 1.f : __expf(x);
}

#define MFMA16(a, b, c) __builtin_amdgcn_mfma_f32_16x16x32_bf16((a), (b), (c), 0, 0, 0)

// ---------- GEMM: C[m][n] = sum_k A[m][k] * Bt[n][k] ----------
// A fp32 [M][lda], Bt fp32 [N][ldb], C fp32 [.][ldc]. M = grid.x*128, K mult of 32.
__global__ __launch_bounds__(256) void gemm_nt(
    const float* __restrict__ A, int lda,
    const float* __restrict__ Bt, int ldb,
    float* __restrict__ C, int ldc,
    int N, int K)
{
    __shared__ short As[128][40];
    __shared__ short Bs[128][40];
    const int row0 = blockIdx.x * 128;
    const int col0 = blockIdx.y * 128;
    const int t = threadIdx.x;
    const int lane = t & 63;
    const int wave = t >> 6;
    const int wr = (wave >> 1) * 64;
    const int wc = (wave & 1) * 64;
    const int l15 = lane & 15;
    const int kg = (lane >> 4) * 8;
    const int rbase = (lane >> 4) * 4;

    f32x4 acc[4][4];
#pragma unroll
    for (int i = 0; i < 4; ++i)
#pragma unroll
        for (int j = 0; j < 4; ++j) acc[i][j] = (f32x4){0.f, 0.f, 0.f, 0.f};

    const int c4 = (t & 7) * 4;
    const int r0 = t >> 3;

    for (int k0 = 0; k0 < K; k0 += 32) {
#pragma unroll
        for (int p = 0; p < 4; ++p) {
            const int rr = r0 + p * 32;
            const float4 av = *(const float4*)(A + (size_t)(row0 + rr) * lda + k0 + c4);
            As[rr][c4 + 0] = f2bf(av.x);
            As[rr][c4 + 1] = f2bf(av.y);
            As[rr][c4 + 2] = f2bf(av.z);
            As[rr][c4 + 3] = f2bf(av.w);
            const int brow = col0 + rr;
            float4 bv = make_float4(0.f, 0.f, 0.f, 0.f);
            if (brow < N) bv = *(const float4*)(Bt + (size_t)brow * ldb + k0 + c4);
            Bs[rr][c4 + 0] = f2bf(bv.x);
            Bs[rr][c4 + 1] = f2bf(bv.y);
            Bs[rr][c4 + 2] = f2bf(bv.z);
            Bs[rr][c4 + 3] = f2bf(bv.w);
        }
        __syncthreads();
        bf16x8 af[4], bfr[4];
#pragma unroll
        for (int i = 0; i < 4; ++i) af[i] = *(const bf16x8*)&As[wr + i * 16 + l15][kg];
#pragma unroll
        for (int j = 0; j < 4; ++j) bfr[j] = *(const bf16x8*)&Bs[wc + j * 16 + l15][kg];
#pragma unroll
        for (int i = 0; i < 4; ++i)
#pragma unroll
            for (int j = 0; j < 4; ++j)
                acc[i][j] = MFMA16(af[i], bfr[j], acc[i][j]);
        __syncthreads();
    }
#pragma unroll
    for (int i = 0; i < 4; ++i) {
#pragma unroll
        for (int j = 0; j < 4; ++j) {
            const int cc = col0 + wc + j * 16 + l15;
            if (cc < N) {
                float* cp = C + (size_t)(row0 + wr + i * 16 + rbase) * ldc + cc;
#pragma unroll
                for (int q = 0; q < 4; ++q) cp[(size_t)q * ldc] = acc[i][j][q];
            }
        }
    }
}

// ---------- RMSNorm (q-lat, kv-lat) + RoPE on k_pe ----------
__global__ __launch_bounds__(256) void rms_rope(
    const float* __restrict__ Y1,
    const float* __restrict__ qw, const float* __restrict__ kvw,
    const float* __restrict__ cosT, const float* __restrict__ sinT,
    float* __restrict__ qn, float* __restrict__ kvn, float* __restrict__ kpe)
{
    __shared__ float red[256];
    const int row = blockIdx.x;
    const int s = row & 4095;
    const int t = threadIdx.x;
    const float* yr = Y1 + (size_t)row * 1088;

    float v0 = yr[t], v1 = yr[t + 256];
    red[t] = v0 * v0 + v1 * v1;
    __syncthreads();
    for (int off = 128; off > 0; off >>= 1) {
        if (t < off) red[t] += red[t + off];
        __syncthreads();
    }
    float rs = rsqrtf(red[0] / 512.f + 1e-6f);
    __syncthreads();
    qn[(size_t)row * 512 + t]       = v0 * rs * qw[t];
    qn[(size_t)row * 512 + t + 256] = v1 * rs * qw[t + 256];

    float u0 = yr[512 + t], u1 = yr[768 + t];
    red[t] = u0 * u0 + u1 * u1;
    __syncthreads();
    for (int off = 128; off > 0; off >>= 1) {
        if (t < off) red[t] += red[t + off];
        __syncthreads();
    }
    float rs2 = rsqrtf(red[0] / 512.f + 1e-6f);
    kvn[(size_t)row * 512 + t]       = u0 * rs2 * kvw[t];
    kvn[(size_t)row * 512 + t + 256] = u1 * rs2 * kvw[t + 256];

    if (t < 32) {
        float xr = yr[1024 + 2 * t], xi = yr[1024 + 2 * t + 1];
        float cc = cosT[(size_t)s * 32 + t], sn = sinT[(size_t)s * 32 + t];
        kpe[(size_t)row * 64 + 2 * t]     = xr * cc - xi * sn;
        kpe[(size_t)row * 64 + 2 * t + 1] = xr * sn + xi * cc;
    }
}

// ---------- build q_ssa: rope on q_pe, elu+1, layout [b][h][s][192] bf16 ----------
__global__ __launch_bounds__(192) void build_q(
    const float* __restrict__ qbig,
    const float* __restrict__ cosT, const float* __restrict__ sinT,
    short* __restrict__ q_ssa)
{
    const int row = blockIdx.x;          // b*4096 + s
    const int s = row & 4095;
    const int b = row >> 12;
    const int d = threadIdx.x;           // 0..191
    const float* qr = qbig + (size_t)row * 3072;
#pragma unroll 1
    for (int h = 0; h < 16; ++h) {
        float val;
        if (d < 128) {
            val = qr[h * 192 + d];
        } else {
            const int p = (d - 128) >> 1;
            const float xr = qr[h * 192 + 128 + 2 * p];
            const float xi = qr[h * 192 + 128 + 2 * p + 1];
            const float cc = cosT[(size_t)s * 32 + p];
            const float sn = sinT[(size_t)s * 32 + p];
            val = ((d & 1) == 0) ? (xr * cc - xi * sn) : (xr * sn + xi * cc);
        }
        val = elu1(val);
        q_ssa[((size_t)(b * 16 + h) * 4096 + s) * 192 + d] = f2bf(val);
    }
}

// ---------- build k_ssa / v_ssa ----------
__global__ __launch_bounds__(256) void build_kv(
    const float* __restrict__ kvbig, const float* __restrict__ kpe,
    short* __restrict__ k_ssa, short* __restrict__ v_ssa)
{
    const int row = blockIdx.x;
    const int s = row & 4095;
    const int b = row >> 12;
    const int t = threadIdx.x;
    const float* kr = kvbig + (size_t)row * 4096;
    const float* pe = kpe + (size_t)row * 64;
#pragma unroll 1
    for (int h = 0; h < 16; ++h) {
        const size_t kbase = ((size_t)(b * 16 + h) * 4096 + s) * 192;
        const size_t vbase = ((size_t)(b * 16 + h) * 4096 + s) * 128;
        if (t < 128) {
            k_ssa[kbase + t] = f2bf(elu1(kr[h * 256 + t]));
            v_ssa[vbase + t] = f2bf(kr[h * 256 + 128 + t]);
        } else if (t < 192) {
            const int d = t - 128;
            k_ssa[kbase + 128 + d] = f2bf(elu1(pe[d]));
        }
    }
}

// ---------- SSA per-chunk: kvc = K^T V ; intra = tril(Q K^T) V ----------
__global__ __launch_bounds__(256) void ssa_chunk(
    const short* __restrict__ q_ssa, const short* __restrict__ k_ssa,
    const short* __restrict__ v_ssa,
    float* __restrict__ kvc, float* __restrict__ attn)
{
    __shared__ short lq[64][200];
    __shared__ short lk[64][200];
    __shared__ short lkt[192][72];
    __shared__ short lvt[128][72];
    __shared__ short lsc[64][72];
    const int c = blockIdx.x, h = blockIdx.y, b = blockIdx.z;
    const int bh = b * 16 + h;
    const short* Q  = q_ssa + ((size_t)bh * 4096 + c * 64) * 192;
    const short* Kc = k_ssa + ((size_t)bh * 4096 + c * 64) * 192;
    const short* Vc = v_ssa + ((size_t)bh * 4096 + c * 64) * 128;
    const int t = threadIdx.x;
    const int lane = t & 63, wave = t >> 6;
    const int l15 = lane & 15, kg = (lane >> 4) * 8, rbase = (lane >> 4) * 4;

    for (int i = t; i < 64 * 48; i += 256) {
        const int row = i / 48, cc4 = (i % 48) * 4;
        ushort4 qv = *(const ushort4*)(Q + (size_t)row * 192 + cc4);
        *(ushort4*)&lq[row][cc4] = qv;
        ushort4 kv4 = *(const ushort4*)(Kc + (size_t)row * 192 + cc4);
        *(ushort4*)&lk[row][cc4] = kv4;
        lkt[cc4 + 0][row] = (short)kv4.x;
        lkt[cc4 + 1][row] = (short)kv4.y;
        lkt[cc4 + 2][row] = (short)kv4.z;
        lkt[cc4 + 3][row] = (short)kv4.w;
    }
    for (int i = t; i < 64 * 32; i += 256) {
        const int row = i >> 5, cc4 = (i & 31) * 4;
        ushort4 vv = *(const ushort4*)(Vc + (size_t)row * 128 + cc4);
        lvt[cc4 + 0][row] = (short)vv.x;
        lvt[cc4 + 1][row] = (short)vv.y;
        lvt[cc4 + 2][row] = (short)vv.z;
        lvt[cc4 + 3][row] = (short)vv.w;
    }
    __syncthreads();

    // kvc: wave handles dk rows [wave*48, wave*48+48), all 128 dv
    {
        f32x4 ac[3][8];
#pragma unroll
        for (int i = 0; i < 3; ++i)
#pragma unroll
            for (int j = 0; j < 8; ++j) ac[i][j] = (f32x4){0.f, 0.f, 0.f, 0.f};
#pragma unroll
        for (int ks = 0; ks < 2; ++ks) {
            bf16x8 af[3], bv[8];
#pragma unroll
            for (int i = 0; i < 3; ++i) af[i] = *(const bf16x8*)&lkt[wave * 48 + i * 16 + l15][ks * 32 + kg];
#pragma unroll
            for (int j = 0; j < 8; ++j) bv[j] = *(const bf16x8*)&lvt[j * 16 + l15][ks * 32 + kg];
#pragma unroll
            for (int i = 0; i < 3; ++i)
#pragma unroll
                for (int j = 0; j < 8; ++j) ac[i][j] = MFMA16(af[i], bv[j], ac[i][j]);
        }
        float* kvp = kvc + ((size_t)bh * 64 + c) * (192 * 128);
#pragma unroll
        for (int i = 0; i < 3; ++i)
#pragma unroll
            for (int j = 0; j < 8; ++j)
#pragma unroll
                for (int q = 0; q < 4; ++q) {
                    const int dk = wave * 48 + i * 16 + rbase + q;
                    const int dv = j * 16 + l15;
                    kvp[(size_t)dk * 128 + dv] = ac[i][j][q];
                }
    }

    // sc = tril(Q K^T), wave handles l-rows [wave*16, wave*16+16)
    {
        f32x4 sc[4];
#pragma unroll
        for (int j = 0; j < 4; ++j) sc[j] = (f32x4){0.f, 0.f, 0.f, 0.f};
#pragma unroll
        for (int ks = 0; ks < 6; ++ks) {
            bf16x8 aq = *(const bf16x8*)&lq[wave * 16 + l15][ks * 32 + kg];
#pragma unroll
            for (int j = 0; j < 4; ++j) {
                bf16x8 bk = *(const bf16x8*)&lk[j * 16 + l15][ks * 32 + kg];
                sc[j] = MFMA16(aq, bk, sc[j]);
            }
        }
#pragma unroll
        for (int j = 0; j < 4; ++j)
#pragma unroll
            for (int q = 0; q < 4; ++q) {
                const int l = wave * 16 + rbase + q;
                const int m = j * 16 + l15;
                const float v = (m <= l) ? sc[j][q] : 0.f;
                lsc[l][m] = f2bf(v);
            }
    }
    __syncthreads();

    // intra = sc @ V
    {
        f32x4 ai[8];
#pragma unroll
        for (int j = 0; j < 8; ++j) ai[j] = (f32x4){0.f, 0.f, 0.f, 0.f};
#pragma unroll
        for (int ks = 0; ks < 2; ++ks) {
            bf16x8 as = *(const bf16x8*)&lsc[wave * 16 + l15][ks * 32 + kg];
#pragma unroll
            for (int j = 0; j < 8; ++j) {
                bf16x8 bv = *(const bf16x8*)&lvt[j * 16 + l15][ks * 32 + kg];
                ai[j] = MFMA16(as, bv, ai[j]);
            }
        }
#pragma unroll
        for (int j = 0; j < 8; ++j)
#pragma unroll
            for (int q = 0; q < 4; ++q) {
                const int l = wave * 16 + rbase + q;
                const int dv = j * 16 + l15;
                attn[((size_t)(b * 4096 + c * 64 + l)) * 2048 + h * 128 + dv] = ai[j][q];
            }
    }
}

// ---------- exclusive cumsum over chunks (in-place) + init_state ----------
__global__ __launch_bounds__(256) void ssa_cumsum(
    float* __restrict__ kvc, const float* __restrict__ init)
{
    const int bh = blockIdx.y;
    const int e = blockIdx.x * 256 + threadIdx.x;  // < 24576
    float stv = init[(size_t)bh * 24576 + e];
    float* p = kvc + (size_t)bh * 64 * 24576 + e;
    for (int cc = 0; cc < 64; ++cc) {
        const float v = *p;
        *p = stv;
        stv += v;
        p += 24576;
    }
}

// ---------- inter = Q @ state; out = (inter + intra) * SCALE ----------
__global__ __launch_bounds__(256) void ssa_inter(
    const short* __restrict__ q_ssa, const float* __restrict__ states,
    float* __restrict__ attn)
{
    __shared__ short lq[64][200];
    __shared__ short lst[128][200];  // states transposed: [dv][dk]
    const int c = blockIdx.x, h = blockIdx.y, b = blockIdx.z;
    const int bh = b * 16 + h;
    const short* Q = q_ssa + ((size_t)bh * 4096 + c * 64) * 192;
    const float* st = states + ((size_t)bh * 64 + c) * (192 * 128);
    const int t = threadIdx.x, lane = t & 63, wave = t >> 6;
    const int l15 = lane & 15, kg = (lane >> 4) * 8, rbase = (lane >> 4) * 4;

    for (int i = t; i < 64 * 48; i += 256) {
        const int row = i / 48, cc4 = (i % 48) * 4;
        *(ushort4*)&lq[row][cc4] = *(const ushort4*)(Q + (size_t)row * 192 + cc4);
    }
    for (int i = t; i < 6144; i += 256) {
        const int dk = i >> 5, cc4 = (i & 31) * 4;
        const float4 sv = *(const float4*)(st + (size_t)dk * 128 + cc4);
        lst[cc4 + 0][dk] = f2bf(sv.x);
        lst[cc4 + 1][dk] = f2bf(sv.y);
        lst[cc4 + 2][dk] = f2bf(sv.z);
        lst[cc4 + 3][dk] = f2bf(sv.w);
    }
    __syncthreads();

    f32x4 ai[8];
#pragma unroll
    for (int j = 0; j < 8; ++j) ai[j] = (f32x4){0.f, 0.f, 0.f, 0.f};
#pragma unroll
    for (int ks = 0; ks < 6; ++ks) {
        bf16x8 aq = *(const bf16x8*)&lq[wave * 16 + l15][ks * 32 + kg];
#pragma unroll
        for (int j = 0; j < 8; ++j) {
            bf16x8 bs = *(const bf16x8*)&lst[j * 16 + l15][ks * 32 + kg];
            ai[j] = MFMA16(aq, bs, ai[j]);
        }
    }
    const float scale = 0.07216878364870322f;  // 192^-0.5
#pragma unroll
    for (int j = 0; j < 8; ++j)
#pragma unroll
        for (int q = 0; q < 4; ++q) {
            const int l = wave * 16 + rbase + q;
            const int dv = j * 16 + l15;
            const size_t off = ((size_t)(b * 4096 + c * 64 + l)) * 2048 + h * 128 + dv;
            attn[off] = (attn[off] + ai[j][q]) * scale;
        }
}

// ---------- launch ----------
extern "C" void kernel_launch(void* const* d_in, const int* in_sizes, int n_in,
                              void* d_out, int out_size, void* d_ws, size_t ws_size,
                              hipStream_t stream) {
    const float* x     = (const float*)d_in[0];
    const float* cosT  = (const float*)d_in[2];
    const float* sinT  = (const float*)d_in[3];
    const float* wq_a  = (const float*)d_in[4];
    const float* wq_b  = (const float*)d_in[5];
    const float* wkv_a = (const float*)d_in[6];
    const float* wkv_b = (const float*)d_in[7];
    const float* wo    = (const float*)d_in[8];
    const float* qw    = (const float*)d_in[9];
    const float* kvw   = (const float*)d_in[10];
    const float* init  = (const float*)d_in[11];
    float* out = (float*)d_out;

    void* base = nullptr;
    hipGetSymbolAddress(&base, HIP_SYMBOL(g_ws));
    char* ws = (char*)base;
    size_t off = 0;
    auto take = [&](size_t bytes) -> char* {
        char* p = ws + off;
        off += (bytes + 255) & ~(size_t)255;
        return p;
    };
    float* big  = (float*)take((size_t)8192 * 4096 * 4);   // Y1 / q_big / kv_big / attn
    float* qn   = (float*)take((size_t)8192 * 512 * 4);
    float* kvn  = (float*)take((size_t)8192 * 512 * 4);
    float* kpe  = (float*)take((size_t)8192 * 64 * 4);
    short* qs   = (short*)take((size_t)2 * 16 * 4096 * 192 * 2);
    short* ksb  = (short*)take((size_t)2 * 16 * 4096 * 192 * 2);
    short* vsb  = (short*)take((size_t)2 * 16 * 4096 * 128 * 2);
    float* kvcB = (float*)take((size_t)2048 * 24576 * 4);
    float* attn = big;

    // 1. Y1 = x @ [wq_a; wkv_a]^T   (cols 0:512 and 512:1088 of a 1088-wide buffer)
    gemm_nt<<<dim3(64, 4), 256, 0, stream>>>(x, 2048, wq_a, 2048, big, 1088, 512, 2048);
    gemm_nt<<<dim3(64, 5), 256, 0, stream>>>(x, 2048, wkv_a, 2048, big + 512, 1088, 576, 2048);
    // 2. RMSNorm + rope(k_pe)
    rms_rope<<<8192, 256, 0, stream>>>(big, qw, kvw, cosT, sinT, qn, kvn, kpe);
    // 3a. q = qn @ wq_b^T
    gemm_nt<<<dim3(64, 24), 256, 0, stream>>>(qn, 512, wq_b, 512, big, 3072, 3072, 512);
    build_q<<<8192, 192, 0, stream>>>(big, cosT, sinT, qs);
    // 3b. kv = kvn @ wkv_b^T
    gemm_nt<<<dim3(64, 32), 256, 0, stream>>>(kvn, 512, wkv_b, 512, big, 4096, 4096, 512);
    build_kv<<<8192, 256, 0, stream>>>(big, kpe, ksb, vsb);
    // 4. SSA
    ssa_chunk<<<dim3(64, 16, 2), 256, 0, stream>>>(qs, ksb, vsb, kvcB, attn);
    ssa_cumsum<<<dim3(96, 32), 256, 0, stream>>>(kvcB, init);
    ssa_inter<<<dim3(64, 16, 2), 256, 0, stream>>>(qs, kvcB, attn);
    // 5. out = attn @ wo^T
    gemm_nt<<<dim3(64, 16), 256, 0, stream>>>(attn, 2048, wo, 2048, out, 2048, 2048, 2048);
}

// Round 3
// 844.961 us; speedup vs baseline: 1.5484x; 1.5484x over previous
//
#include <hip/hip_runtime.h>

// ---------- static device workspace ----------
static __device__ __align__(256) unsigned char g_ws[645200000];

// ---------- types ----------
typedef __attribute__((ext_vector_type(8))) __bf16 bf16x8;
typedef __attribute__((ext_vector_type(4))) float  f32x4;

__device__ __forceinline__ short f2bf(float f) {
    union { float f; unsigned u; } v; v.f = f;
    unsigned r = v.u + 0x7FFFu + ((v.u >> 16) & 1u);
    return (short)(r >> 16);
}
__device__ __forceinline__ float bf2f(unsigned short u) {
    union { unsigned u; float f; } v; v.u = ((unsigned)u) << 16;
    return v.f;
}
__device__ __forceinline__ float elu1(float x) {
    return x > 0.f ? x + 1.f : __expf(x);
}
__device__ __forceinline__ void gload_lds16(const void* g, void* l) {
    __builtin_amdgcn_global_load_lds(
        (const __attribute__((address_space(1))) unsigned int*)g,
        (__attribute__((address_space(3))) unsigned int*)l, 16, 0, 0);
}

#define MFMA16(a, b, c) __builtin_amdgcn_mfma_f32_16x16x32_bf16((a), (b), (c), 0, 0, 0)

// ---------- fp32 -> bf16 convert ----------
__global__ __launch_bounds__(256) void cvt_bf16(
    const float* __restrict__ src, short* __restrict__ dst, int n)
{
    const int i = (blockIdx.x * 256 + threadIdx.x) * 4;
    if (i < n) {
        const float4 v = *(const float4*)(src + i);
        ushort4 o;
        o.x = (unsigned short)f2bf(v.x);
        o.y = (unsigned short)f2bf(v.y);
        o.z = (unsigned short)f2bf(v.z);
        o.w = (unsigned short)f2bf(v.w);
        *(ushort4*)(dst + i) = o;
    }
}

// ---------- GEMM (m97 structure): C = A(bf16) @ Bt(bf16)^T ----------
// A [M][lda] bf16, Bt [Npad][ldb] bf16 (pad rows zeroed), C [M][ldc].
// grid = (M/128, Npad/128), 256 threads. K mult of 32. lda/ldb rows 16B-aligned.
template <int OUT_BF16>
__global__ __launch_bounds__(256) void gemm_lds(
    const short* __restrict__ A, int lda,
    const short* __restrict__ Bt, int ldb,
    void* __restrict__ Cv, int ldc,
    int Nvalid, int K)
{
    __shared__ short As[128 * 32];
    __shared__ short Bs[128 * 32];
    const int row0 = blockIdx.x * 128;
    const int col0 = blockIdx.y * 128;
    const int t = threadIdx.x;
    const int lane = t & 63;
    const int wave = t >> 6;
    const int wr = (wave >> 1) * 64;
    const int wc = (wave & 1) * 64;
    const int l15 = lane & 15;
    const int kg = (lane >> 4) * 8;
    const int rbase = (lane >> 4) * 4;

    // staging geometry: wave w stages rows [w*32, w*32+32); issue i covers 16 rows.
    const int srow = (lane >> 2);          // 0..15 within an issue
    const int sbyte = (lane & 3) * 16;     // byte slot within 64B row

    f32x4 acc[4][4];
#pragma unroll
    for (int i = 0; i < 4; ++i)
#pragma unroll
        for (int j = 0; j < 4; ++j) acc[i][j] = (f32x4){0.f, 0.f, 0.f, 0.f};

    const char* aBase = (const char*)A + ((size_t)(row0 + wave * 32 + srow) * lda) * 2 + sbyte;
    const char* bBase = (const char*)Bt + ((size_t)(col0 + wave * 32 + srow) * ldb) * 2 + sbyte;
    const size_t aRow16 = (size_t)lda * 32;   // bytes for 16 rows
    const size_t bRow16 = (size_t)ldb * 32;

    for (int k0 = 0; k0 < K; k0 += 32) {
        const size_t kb = (size_t)k0 * 2;
        gload_lds16(aBase + kb,          &As[(wave * 32) * 32]);
        gload_lds16(aBase + kb + aRow16, &As[(wave * 32 + 16) * 32]);
        gload_lds16(bBase + kb,          &Bs[(wave * 32) * 32]);
        gload_lds16(bBase + kb + bRow16, &Bs[(wave * 32 + 16) * 32]);
        __syncthreads();
        bf16x8 af[4], bfr[4];
#pragma unroll
        for (int i = 0; i < 4; ++i) af[i] = *(const bf16x8*)&As[(wr + i * 16 + l15) * 32 + kg];
#pragma unroll
        for (int j = 0; j < 4; ++j) bfr[j] = *(const bf16x8*)&Bs[(wc + j * 16 + l15) * 32 + kg];
#pragma unroll
        for (int i = 0; i < 4; ++i)
#pragma unroll
            for (int j = 0; j < 4; ++j)
                acc[i][j] = MFMA16(af[i], bfr[j], acc[i][j]);
        __syncthreads();
    }
#pragma unroll
    for (int i = 0; i < 4; ++i) {
#pragma unroll
        for (int j = 0; j < 4; ++j) {
            const int cc = col0 + wc + j * 16 + l15;
            if (cc < Nvalid) {
#pragma unroll
                for (int q = 0; q < 4; ++q) {
                    const size_t off = (size_t)(row0 + wr + i * 16 + rbase + q) * ldc + cc;
                    if (OUT_BF16) ((short*)Cv)[off] = f2bf(acc[i][j][q]);
                    else          ((float*)Cv)[off] = acc[i][j][q];
                }
            }
        }
    }
}

// ---------- RMSNorm (q-lat, kv-lat) + RoPE on k_pe; bf16 in, bf16 out ----------
__global__ __launch_bounds__(256) void rms_rope(
    const short* __restrict__ Y1,
    const float* __restrict__ qw, const float* __restrict__ kvw,
    const float* __restrict__ cosT, const float* __restrict__ sinT,
    short* __restrict__ qn, short* __restrict__ kvn, float* __restrict__ kpe)
{
    __shared__ float red[256];
    const int row = blockIdx.x;
    const int s = row & 4095;
    const int t = threadIdx.x;
    const unsigned short* yr = (const unsigned short*)(Y1 + (size_t)row * 1088);

    float v0 = bf2f(yr[t]), v1 = bf2f(yr[t + 256]);
    red[t] = v0 * v0 + v1 * v1;
    __syncthreads();
    for (int off = 128; off > 0; off >>= 1) {
        if (t < off) red[t] += red[t + off];
        __syncthreads();
    }
    float rs = rsqrtf(red[0] / 512.f + 1e-6f);
    __syncthreads();
    qn[(size_t)row * 512 + t]       = f2bf(v0 * rs * qw[t]);
    qn[(size_t)row * 512 + t + 256] = f2bf(v1 * rs * qw[t + 256]);

    float u0 = bf2f(yr[512 + t]), u1 = bf2f(yr[768 + t]);
    red[t] = u0 * u0 + u1 * u1;
    __syncthreads();
    for (int off = 128; off > 0; off >>= 1) {
        if (t < off) red[t] += red[t + off];
        __syncthreads();
    }
    float rs2 = rsqrtf(red[0] / 512.f + 1e-6f);
    kvn[(size_t)row * 512 + t]       = f2bf(u0 * rs2 * kvw[t]);
    kvn[(size_t)row * 512 + t + 256] = f2bf(u1 * rs2 * kvw[t + 256]);

    if (t < 32) {
        float xr = bf2f(yr[1024 + 2 * t]), xi = bf2f(yr[1024 + 2 * t + 1]);
        float cc = cosT[(size_t)s * 32 + t], sn = sinT[(size_t)s * 32 + t];
        kpe[(size_t)row * 64 + 2 * t]     = xr * cc - xi * sn;
        kpe[(size_t)row * 64 + 2 * t + 1] = xr * sn + xi * cc;
    }
}

// ---------- build q_ssa: rope on q_pe, elu+1, layout [b][h][s][192] bf16 ----------
__global__ __launch_bounds__(192) void build_q(
    const short* __restrict__ qbig,
    const float* __restrict__ cosT, const float* __restrict__ sinT,
    short* __restrict__ q_ssa)
{
    const int row = blockIdx.x;          // b*4096 + s
    const int s = row & 4095;
    const int b = row >> 12;
    const int d = threadIdx.x;           // 0..191
    const unsigned short* qr = (const unsigned short*)(qbig + (size_t)row * 3072);
#pragma unroll 1
    for (int h = 0; h < 16; ++h) {
        float val;
        if (d < 128) {
            val = bf2f(qr[h * 192 + d]);
        } else {
            const int p = (d - 128) >> 1;
            const float xr = bf2f(qr[h * 192 + 128 + 2 * p]);
            const float xi = bf2f(qr[h * 192 + 128 + 2 * p + 1]);
            const float cc = cosT[(size_t)s * 32 + p];
            const float sn = sinT[(size_t)s * 32 + p];
            val = ((d & 1) == 0) ? (xr * cc - xi * sn) : (xr * sn + xi * cc);
        }
        val = elu1(val);
        q_ssa[((size_t)(b * 16 + h) * 4096 + s) * 192 + d] = f2bf(val);
    }
}

// ---------- build k_ssa / v_ssa ----------
__global__ __launch_bounds__(256) void build_kv(
    const short* __restrict__ kvbig, const float* __restrict__ kpe,
    short* __restrict__ k_ssa, short* __restrict__ v_ssa)
{
    const int row = blockIdx.x;
    const int s = row & 4095;
    const int b = row >> 12;
    const int t = threadIdx.x;
    const unsigned short* kr = (const unsigned short*)(kvbig + (size_t)row * 4096);
    const float* pe = kpe + (size_t)row * 64;
#pragma unroll 1
    for (int h = 0; h < 16; ++h) {
        const size_t kbase = ((size_t)(b * 16 + h) * 4096 + s) * 192;
        const size_t vbase = ((size_t)(b * 16 + h) * 4096 + s) * 128;
        if (t < 128) {
            k_ssa[kbase + t] = f2bf(elu1(bf2f(kr[h * 256 + t])));
            v_ssa[vbase + t] = (short)kr[h * 256 + 128 + t];
        } else if (t < 192) {
            const int d = t - 128;
            k_ssa[kbase + 128 + d] = f2bf(elu1(pe[d]));
        }
    }
}

// ---------- SSA per-chunk: kvc = K^T V ; intra = tril(Q K^T) V ----------
__global__ __launch_bounds__(256) void ssa_chunk(
    const short* __restrict__ q_ssa, const short* __restrict__ k_ssa,
    const short* __restrict__ v_ssa,
    float* __restrict__ kvc, float* __restrict__ intra)
{
    __shared__ short lq[64][200];
    __shared__ short lk[64][200];
    __shared__ short lkt[192][72];
    __shared__ short lvt[128][72];
    __shared__ short lsc[64][72];
    const int c = blockIdx.x, h = blockIdx.y, b = blockIdx.z;
    const int bh = b * 16 + h;
    const short* Q  = q_ssa + ((size_t)bh * 4096 + c * 64) * 192;
    const short* Kc = k_ssa + ((size_t)bh * 4096 + c * 64) * 192;
    const short* Vc = v_ssa + ((size_t)bh * 4096 + c * 64) * 128;
    const int t = threadIdx.x;
    const int lane = t & 63, wave = t >> 6;
    const int l15 = lane & 15, kg = (lane >> 4) * 8, rbase = (lane >> 4) * 4;

    for (int i = t; i < 64 * 48; i += 256) {
        const int row = i / 48, cc4 = (i % 48) * 4;
        ushort4 qv = *(const ushort4*)(Q + (size_t)row * 192 + cc4);
        *(ushort4*)&lq[row][cc4] = qv;
        ushort4 kv4 = *(const ushort4*)(Kc + (size_t)row * 192 + cc4);
        *(ushort4*)&lk[row][cc4] = kv4;
        lkt[cc4 + 0][row] = (short)kv4.x;
        lkt[cc4 + 1][row] = (short)kv4.y;
        lkt[cc4 + 2][row] = (short)kv4.z;
        lkt[cc4 + 3][row] = (short)kv4.w;
    }
    for (int i = t; i < 64 * 32; i += 256) {
        const int row = i >> 5, cc4 = (i & 31) * 4;
        ushort4 vv = *(const ushort4*)(Vc + (size_t)row * 128 + cc4);
        lvt[cc4 + 0][row] = (short)vv.x;
        lvt[cc4 + 1][row] = (short)vv.y;
        lvt[cc4 + 2][row] = (short)vv.z;
        lvt[cc4 + 3][row] = (short)vv.w;
    }
    __syncthreads();

    // kvc: wave handles dk rows [wave*48, wave*48+48), all 128 dv
    {
        f32x4 ac[3][8];
#pragma unroll
        for (int i = 0; i < 3; ++i)
#pragma unroll
            for (int j = 0; j < 8; ++j) ac[i][j] = (f32x4){0.f, 0.f, 0.f, 0.f};
#pragma unroll
        for (int ks = 0; ks < 2; ++ks) {
            bf16x8 af[3], bv[8];
#pragma unroll
            for (int i = 0; i < 3; ++i) af[i] = *(const bf16x8*)&lkt[wave * 48 + i * 16 + l15][ks * 32 + kg];
#pragma unroll
            for (int j = 0; j < 8; ++j) bv[j] = *(const bf16x8*)&lvt[j * 16 + l15][ks * 32 + kg];
#pragma unroll
            for (int i = 0; i < 3; ++i)
#pragma unroll
                for (int j = 0; j < 8; ++j) ac[i][j] = MFMA16(af[i], bv[j], ac[i][j]);
        }
        float* kvp = kvc + ((size_t)bh * 64 + c) * (192 * 128);
#pragma unroll
        for (int i = 0; i < 3; ++i)
#pragma unroll
            for (int j = 0; j < 8; ++j)
#pragma unroll
                for (int q = 0; q < 4; ++q) {
                    const int dk = wave * 48 + i * 16 + rbase + q;
                    const int dv = j * 16 + l15;
                    kvp[(size_t)dk * 128 + dv] = ac[i][j][q];
                }
    }

    // sc = tril(Q K^T), wave handles l-rows [wave*16, wave*16+16)
    {
        f32x4 sc[4];
#pragma unroll
        for (int j = 0; j < 4; ++j) sc[j] = (f32x4){0.f, 0.f, 0.f, 0.f};
#pragma unroll
        for (int ks = 0; ks < 6; ++ks) {
            bf16x8 aq = *(const bf16x8*)&lq[wave * 16 + l15][ks * 32 + kg];
#pragma unroll
            for (int j = 0; j < 4; ++j) {
                bf16x8 bk = *(const bf16x8*)&lk[j * 16 + l15][ks * 32 + kg];
                sc[j] = MFMA16(aq, bk, sc[j]);
            }
        }
#pragma unroll
        for (int j = 0; j < 4; ++j)
#pragma unroll
            for (int q = 0; q < 4; ++q) {
                const int l = wave * 16 + rbase + q;
                const int m = j * 16 + l15;
                const float v = (m <= l) ? sc[j][q] : 0.f;
                lsc[l][m] = f2bf(v);
            }
    }
    __syncthreads();

    // intra = sc @ V
    {
        f32x4 ai[8];
#pragma unroll
        for (int j = 0; j < 8; ++j) ai[j] = (f32x4){0.f, 0.f, 0.f, 0.f};
#pragma unroll
        for (int ks = 0; ks < 2; ++ks) {
            bf16x8 as = *(const bf16x8*)&lsc[wave * 16 + l15][ks * 32 + kg];
#pragma unroll
            for (int j = 0; j < 8; ++j) {
                bf16x8 bv = *(const bf16x8*)&lvt[j * 16 + l15][ks * 32 + kg];
                ai[j] = MFMA16(as, bv, ai[j]);
            }
        }
#pragma unroll
        for (int j = 0; j < 8; ++j)
#pragma unroll
            for (int q = 0; q < 4; ++q) {
                const int l = wave * 16 + rbase + q;
                const int dv = j * 16 + l15;
                intra[((size_t)(b * 4096 + c * 64 + l)) * 2048 + h * 128 + dv] = ai[j][q];
            }
    }
}

// ---------- exclusive cumsum over chunks (in-place) + init_state ----------
__global__ __launch_bounds__(256) void ssa_cumsum(
    float* __restrict__ kvc, const float* __restrict__ init)
{
    const int bh = blockIdx.y;
    const int e = blockIdx.x * 256 + threadIdx.x;  // < 24576
    float stv = init[(size_t)bh * 24576 + e];
    float* p = kvc + (size_t)bh * 64 * 24576 + e;
    for (int cc = 0; cc < 64; ++cc) {
        const float v = *p;
        *p = stv;
        stv += v;
        p += 24576;
    }
}

// ---------- inter = Q @ state; attnb = (inter + intra) * SCALE (bf16) ----------
__global__ __launch_bounds__(256) void ssa_inter(
    const short* __restrict__ q_ssa, const float* __restrict__ states,
    const float* __restrict__ intra, short* __restrict__ attnb)
{
    __shared__ short lq[64][200];
    __shared__ short lst[128][200];  // states transposed: [dv][dk]
    const int c = blockIdx.x, h = blockIdx.y, b = blockIdx.z;
    const int bh = b * 16 + h;
    const short* Q = q_ssa + ((size_t)bh * 4096 + c * 64) * 192;
    const float* st = states + ((size_t)bh * 64 + c) * (192 * 128);
    const int t = threadIdx.x, lane = t & 63, wave = t >> 6;
    const int l15 = lane & 15, kg = (lane >> 4) * 8, rbase = (lane >> 4) * 4;

    for (int i = t; i < 64 * 48; i += 256) {
        const int row = i / 48, cc4 = (i % 48) * 4;
        *(ushort4*)&lq[row][cc4] = *(const ushort4*)(Q + (size_t)row * 192 + cc4);
    }
    for (int i = t; i < 6144; i += 256) {
        const int dk = i >> 5, cc4 = (i & 31) * 4;
        const float4 sv = *(const float4*)(st + (size_t)dk * 128 + cc4);
        lst[cc4 + 0][dk] = f2bf(sv.x);
        lst[cc4 + 1][dk] = f2bf(sv.y);
        lst[cc4 + 2][dk] = f2bf(sv.z);
        lst[cc4 + 3][dk] = f2bf(sv.w);
    }
    __syncthreads();

    f32x4 ai[8];
#pragma unroll
    for (int j = 0; j < 8; ++j) ai[j] = (f32x4){0.f, 0.f, 0.f, 0.f};
#pragma unroll
    for (int ks = 0; ks < 6; ++ks) {
        bf16x8 aq = *(const bf16x8*)&lq[wave * 16 + l15][ks * 32 + kg];
#pragma unroll
        for (int j = 0; j < 8; ++j) {
            bf16x8 bs = *(const bf16x8*)&lst[j * 16 + l15][ks * 32 + kg];
            ai[j] = MFMA16(aq, bs, ai[j]);
        }
    }
    const float scale = 0.07216878364870322f;  // 192^-0.5
#pragma unroll
    for (int j = 0; j < 8; ++j)
#pragma unroll
        for (int q = 0; q < 4; ++q) {
            const int l = wave * 16 + rbase + q;
            const int dv = j * 16 + l15;
            const size_t off = ((size_t)(b * 4096 + c * 64 + l)) * 2048 + h * 128 + dv;
            attnb[off] = f2bf((intra[off] + ai[j][q]) * scale);
        }
}

// ---------- launch ----------
extern "C" void kernel_launch(void* const* d_in, const int* in_sizes, int n_in,
                              void* d_out, int out_size, void* d_ws, size_t ws_size,
                              hipStream_t stream) {
    const float* x     = (const float*)d_in[0];
    const float* cosT  = (const float*)d_in[2];
    const float* sinT  = (const float*)d_in[3];
    const float* wq_a  = (const float*)d_in[4];
    const float* wq_b  = (const float*)d_in[5];
    const float* wkv_a = (const float*)d_in[6];
    const float* wkv_b = (const float*)d_in[7];
    const float* wo    = (const float*)d_in[8];
    const float* qw    = (const float*)d_in[9];
    const float* kvw   = (const float*)d_in[10];
    const float* init  = (const float*)d_in[11];
    float* out = (float*)d_out;

    void* base = nullptr;
    hipGetSymbolAddress(&base, HIP_SYMBOL(g_ws));
    char* ws = (char*)base;
    size_t off = 0;
    auto take = [&](size_t bytes) -> char* {
        char* p = ws + off;
        off += (bytes + 255) & ~(size_t)255;
        return p;
    };
    short* xb    = (short*)take((size_t)8192 * 2048 * 2);
    short* wab   = (short*)take((size_t)1152 * 2048 * 2);   // [wq_a;wkv_a;pad]
    short* wqbb  = (short*)take((size_t)3072 * 512 * 2);
    short* wkvbb = (short*)take((size_t)4096 * 512 * 2);
    short* wob   = (short*)take((size_t)2048 * 2048 * 2);
    short* y1b   = (short*)take((size_t)8192 * 1088 * 2);
    short* qnb   = (short*)take((size_t)8192 * 512 * 2);
    short* kvnb  = (short*)take((size_t)8192 * 512 * 2);
    float* kpe   = (float*)take((size_t)8192 * 64 * 4);
    short* qbig  = (short*)take((size_t)8192 * 3072 * 2);
    short* kvbig = (short*)take((size_t)8192 * 4096 * 2);
    short* qs    = (short*)take((size_t)2 * 16 * 4096 * 192 * 2);
    short* ksb   = (short*)take((size_t)2 * 16 * 4096 * 192 * 2);
    short* vsb   = (short*)take((size_t)2 * 16 * 4096 * 128 * 2);
    float* kvcB  = (float*)take((size_t)2048 * 24576 * 4);
    float* intra = (float*)take((size_t)8192 * 2048 * 4);
    short* attnb = (short*)take((size_t)8192 * 2048 * 2);

    // 0. convert inputs/weights to bf16
    cvt_bf16<<<(8192 * 2048 / 4 + 255) / 256, 256, 0, stream>>>(x, xb, 8192 * 2048);
    cvt_bf16<<<(512 * 2048 / 4 + 255) / 256, 256, 0, stream>>>(wq_a, wab, 512 * 2048);
    cvt_bf16<<<(576 * 2048 / 4 + 255) / 256, 256, 0, stream>>>(wkv_a, wab + (size_t)512 * 2048, 576 * 2048);
    hipMemsetAsync(wab + (size_t)1088 * 2048, 0, (size_t)64 * 2048 * 2, stream);
    cvt_bf16<<<(3072 * 512 / 4 + 255) / 256, 256, 0, stream>>>(wq_b, wqbb, 3072 * 512);
    cvt_bf16<<<(4096 * 512 / 4 + 255) / 256, 256, 0, stream>>>(wkv_b, wkvbb, 4096 * 512);
    cvt_bf16<<<(2048 * 2048 / 4 + 255) / 256, 256, 0, stream>>>(wo, wob, 2048 * 2048);

    // 1. Y1 = x @ [wq_a; wkv_a]^T  (bf16 out, 1088 wide)
    gemm_lds<1><<<dim3(64, 9), 256, 0, stream>>>(xb, 2048, wab, 2048, y1b, 1088, 1088, 2048);
    // 2. RMSNorm + rope(k_pe)
    rms_rope<<<8192, 256, 0, stream>>>(y1b, qw, kvw, cosT, sinT, qnb, kvnb, kpe);
    // 3a. q = qn @ wq_b^T
    gemm_lds<1><<<dim3(64, 24), 256, 0, stream>>>(qnb, 512, wqbb, 512, qbig, 3072, 3072, 512);
    build_q<<<8192, 192, 0, stream>>>(qbig, cosT, sinT, qs);
    // 3b. kv = kvn @ wkv_b^T
    gemm_lds<1><<<dim3(64, 32), 256, 0, stream>>>(kvnb, 512, wkvbb, 512, kvbig, 4096, 4096, 512);
    build_kv<<<8192, 256, 0, stream>>>(kvbig, kpe, ksb, vsb);
    // 4. SSA
    ssa_chunk<<<dim3(64, 16, 2), 256, 0, stream>>>(qs, ksb, vsb, kvcB, intra);
    ssa_cumsum<<<dim3(96, 32), 256, 0, stream>>>(kvcB, init);
    ssa_inter<<<dim3(64, 16, 2), 256, 0, stream>>>(qs, kvcB, intra, attnb);
    // 5. out = attn @ wo^T (fp32 out)
    gemm_lds<0><<<dim3(64, 16), 256, 0, stream>>>(attnb, 2048, wob, 2048, out, 2048, 2048, 2048);
}

// Round 4
// 688.754 us; speedup vs baseline: 1.8996x; 1.2268x over previous
//
#include <hip/hip_runtime.h>

// ---------- static device workspace ----------
static __device__ __align__(256) unsigned char g_ws[645200000];

// ---------- types ----------
typedef __attribute__((ext_vector_type(8))) __bf16 bf16x8;
typedef __attribute__((ext_vector_type(4))) float  f32x4;
typedef __attribute__((ext_vector_type(8))) unsigned short u16x8;

__device__ __forceinline__ short f2bf(float f) {
    union { float f; unsigned u; } v; v.f = f;
    unsigned r = v.u + 0x7FFFu + ((v.u >> 16) & 1u);
    return (short)(r >> 16);
}
__device__ __forceinline__ float bf2f(unsigned short u) {
    union { unsigned u; float f; } v; v.u = ((unsigned)u) << 16;
    return v.f;
}
__device__ __forceinline__ float elu1(float x) {
    return x > 0.f ? x + 1.f : __expf(x);
}
__device__ __forceinline__ void gload_lds16(const void* g, void* l) {
    __builtin_amdgcn_global_load_lds(
        (const __attribute__((address_space(1))) unsigned int*)g,
        (__attribute__((address_space(3))) unsigned int*)l, 16, 0, 0);
}

#define MFMA16(a, b, c) __builtin_amdgcn_mfma_f32_16x16x32_bf16((a), (b), (c), 0, 0, 0)

// ---------- fp32 -> bf16 convert ----------
__global__ __launch_bounds__(256) void cvt_bf16(
    const float* __restrict__ src, short* __restrict__ dst, int n)
{
    const int i = (blockIdx.x * 256 + threadIdx.x) * 4;
    if (i < n) {
        const float4 v = *(const float4*)(src + i);
        ushort4 o;
        o.x = (unsigned short)f2bf(v.x);
        o.y = (unsigned short)f2bf(v.y);
        o.z = (unsigned short)f2bf(v.z);
        o.w = (unsigned short)f2bf(v.w);
        *(ushort4*)(dst + i) = o;
    }
}

// ---------- GEMM (m97 structure): C = A(bf16) @ Bt(bf16)^T ----------
template <int OUT_BF16>
__global__ __launch_bounds__(256) void gemm_lds(
    const short* __restrict__ A, int lda,
    const short* __restrict__ Bt, int ldb,
    void* __restrict__ Cv, int ldc,
    int Nvalid, int K)
{
    __shared__ short As[128 * 32];
    __shared__ short Bs[128 * 32];
    const int row0 = blockIdx.x * 128;
    const int col0 = blockIdx.y * 128;
    const int t = threadIdx.x;
    const int lane = t & 63;
    const int wave = t >> 6;
    const int wr = (wave >> 1) * 64;
    const int wc = (wave & 1) * 64;
    const int l15 = lane & 15;
    const int kg = (lane >> 4) * 8;
    const int rbase = (lane >> 4) * 4;

    const int srow = (lane >> 2);
    const int sbyte = (lane & 3) * 16;

    f32x4 acc[4][4];
#pragma unroll
    for (int i = 0; i < 4; ++i)
#pragma unroll
        for (int j = 0; j < 4; ++j) acc[i][j] = (f32x4){0.f, 0.f, 0.f, 0.f};

    const char* aBase = (const char*)A + ((size_t)(row0 + wave * 32 + srow) * lda) * 2 + sbyte;
    const char* bBase = (const char*)Bt + ((size_t)(col0 + wave * 32 + srow) * ldb) * 2 + sbyte;
    const size_t aRow16 = (size_t)lda * 32;
    const size_t bRow16 = (size_t)ldb * 32;

    for (int k0 = 0; k0 < K; k0 += 32) {
        const size_t kb = (size_t)k0 * 2;
        gload_lds16(aBase + kb,          &As[(wave * 32) * 32]);
        gload_lds16(aBase + kb + aRow16, &As[(wave * 32 + 16) * 32]);
        gload_lds16(bBase + kb,          &Bs[(wave * 32) * 32]);
        gload_lds16(bBase + kb + bRow16, &Bs[(wave * 32 + 16) * 32]);
        __syncthreads();
        bf16x8 af[4], bfr[4];
#pragma unroll
        for (int i = 0; i < 4; ++i) af[i] = *(const bf16x8*)&As[(wr + i * 16 + l15) * 32 + kg];
#pragma unroll
        for (int j = 0; j < 4; ++j) bfr[j] = *(const bf16x8*)&Bs[(wc + j * 16 + l15) * 32 + kg];
#pragma unroll
        for (int i = 0; i < 4; ++i)
#pragma unroll
            for (int j = 0; j < 4; ++j)
                acc[i][j] = MFMA16(af[i], bfr[j], acc[i][j]);
        __syncthreads();
    }
#pragma unroll
    for (int i = 0; i < 4; ++i) {
#pragma unroll
        for (int j = 0; j < 4; ++j) {
            const int cc = col0 + wc + j * 16 + l15;
            if (cc < Nvalid) {
#pragma unroll
                for (int q = 0; q < 4; ++q) {
                    const size_t off = (size_t)(row0 + wr + i * 16 + rbase + q) * ldc + cc;
                    if (OUT_BF16) ((short*)Cv)[off] = f2bf(acc[i][j][q]);
                    else          ((float*)Cv)[off] = acc[i][j][q];
                }
            }
        }
    }
}

// ---------- RMSNorm (q-lat, kv-lat) + RoPE on k_pe ----------
__global__ __launch_bounds__(256) void rms_rope(
    const short* __restrict__ Y1,
    const float* __restrict__ qw, const float* __restrict__ kvw,
    const float* __restrict__ cosT, const float* __restrict__ sinT,
    short* __restrict__ qn, short* __restrict__ kvn, float* __restrict__ kpe)
{
    __shared__ float red[256];
    const int row = blockIdx.x;
    const int s = row & 4095;
    const int t = threadIdx.x;
    const unsigned short* yr = (const unsigned short*)(Y1 + (size_t)row * 1088);

    float v0 = bf2f(yr[t]), v1 = bf2f(yr[t + 256]);
    red[t] = v0 * v0 + v1 * v1;
    __syncthreads();
    for (int off = 128; off > 0; off >>= 1) {
        if (t < off) red[t] += red[t + off];
        __syncthreads();
    }
    float rs = rsqrtf(red[0] / 512.f + 1e-6f);
    __syncthreads();
    qn[(size_t)row * 512 + t]       = f2bf(v0 * rs * qw[t]);
    qn[(size_t)row * 512 + t + 256] = f2bf(v1 * rs * qw[t + 256]);

    float u0 = bf2f(yr[512 + t]), u1 = bf2f(yr[768 + t]);
    red[t] = u0 * u0 + u1 * u1;
    __syncthreads();
    for (int off = 128; off > 0; off >>= 1) {
        if (t < off) red[t] += red[t + off];
        __syncthreads();
    }
    float rs2 = rsqrtf(red[0] / 512.f + 1e-6f);
    kvn[(size_t)row * 512 + t]       = f2bf(u0 * rs2 * kvw[t]);
    kvn[(size_t)row * 512 + t + 256] = f2bf(u1 * rs2 * kvw[t + 256]);

    if (t < 32) {
        float xr = bf2f(yr[1024 + 2 * t]), xi = bf2f(yr[1024 + 2 * t + 1]);
        float cc = cosT[(size_t)s * 32 + t], sn = sinT[(size_t)s * 32 + t];
        kpe[(size_t)row * 64 + 2 * t]     = xr * cc - xi * sn;
        kpe[(size_t)row * 64 + 2 * t + 1] = xr * sn + xi * cc;
    }
}

// ---------- build q_ssa ----------
__global__ __launch_bounds__(192) void build_q(
    const short* __restrict__ qbig,
    const float* __restrict__ cosT, const float* __restrict__ sinT,
    short* __restrict__ q_ssa)
{
    const int row = blockIdx.x;
    const int s = row & 4095;
    const int b = row >> 12;
    const int d = threadIdx.x;
    const unsigned short* qr = (const unsigned short*)(qbig + (size_t)row * 3072);
#pragma unroll 1
    for (int h = 0; h < 16; ++h) {
        float val;
        if (d < 128) {
            val = bf2f(qr[h * 192 + d]);
        } else {
            const int p = (d - 128) >> 1;
            const float xr = bf2f(qr[h * 192 + 128 + 2 * p]);
            const float xi = bf2f(qr[h * 192 + 128 + 2 * p + 1]);
            const float cc = cosT[(size_t)s * 32 + p];
            const float sn = sinT[(size_t)s * 32 + p];
            val = ((d & 1) == 0) ? (xr * cc - xi * sn) : (xr * sn + xi * cc);
        }
        val = elu1(val);
        q_ssa[((size_t)(b * 16 + h) * 4096 + s) * 192 + d] = f2bf(val);
    }
}

// ---------- build k_ssa / v_ssa ----------
__global__ __launch_bounds__(256) void build_kv(
    const short* __restrict__ kvbig, const float* __restrict__ kpe,
    short* __restrict__ k_ssa, short* __restrict__ v_ssa)
{
    const int row = blockIdx.x;
    const int s = row & 4095;
    const int b = row >> 12;
    const int t = threadIdx.x;
    const unsigned short* kr = (const unsigned short*)(kvbig + (size_t)row * 4096);
    const float* pe = kpe + (size_t)row * 64;
#pragma unroll 1
    for (int h = 0; h < 16; ++h) {
        const size_t kbase = ((size_t)(b * 16 + h) * 4096 + s) * 192;
        const size_t vbase = ((size_t)(b * 16 + h) * 4096 + s) * 128;
        if (t < 128) {
            k_ssa[kbase + t] = f2bf(elu1(bf2f(kr[h * 256 + t])));
            v_ssa[vbase + t] = (short)kr[h * 256 + 128 + t];
        } else if (t < 192) {
            const int d = t - 128;
            k_ssa[kbase + 128 + d] = f2bf(elu1(pe[d]));
        }
    }
}

// ---------- transpose init_state [bh][dk][dv] -> [bh][dv][dk] ----------
__global__ __launch_bounds__(256) void init_t_kern(
    const float* __restrict__ init, float* __restrict__ initT)
{
    __shared__ float tile[32][33];
    const int bh = blockIdx.y;
    const int tk = blockIdx.x % 6, tv = blockIdx.x / 6;
    const int r0 = threadIdx.x >> 5, c = threadIdx.x & 31;
    const float* src = init + (size_t)bh * 24576;
    float* dst = initT + (size_t)bh * 24576;
#pragma unroll
    for (int p = 0; p < 4; ++p) {
        const int rr = r0 + 8 * p;
        tile[rr][c] = src[(size_t)(tk * 32 + rr) * 128 + tv * 32 + c];
    }
    __syncthreads();
#pragma unroll
    for (int p = 0; p < 4; ++p) {
        const int rr = r0 + 8 * p;
        dst[(size_t)(tv * 32 + rr) * 192 + tk * 32 + c] = tile[c][rr];
    }
}

// ---------- per-chunk kv^T = V^T K, bf16 transposed output [dv][dk] ----------
__global__ __launch_bounds__(256, 3) void ssa_kv(
    const short* __restrict__ k_ssa, const short* __restrict__ v_ssa,
    short* __restrict__ kvcT)
{
    __shared__ short smem[25600];                    // 51200 B
    short (*lkt)[72] = (short(*)[72])smem;           // [192][72]
    short (*lvt)[72] = (short(*)[72])(smem + 192 * 72);  // [128][72]
    short (*outT)[200] = (short(*)[200])smem;        // [128][200] (alias)
    const int c = blockIdx.x, h = blockIdx.y, b = blockIdx.z;
    const int bh = b * 16 + h;
    const short* Kc = k_ssa + ((size_t)bh * 4096 + c * 64) * 192;
    const short* Vc = v_ssa + ((size_t)bh * 4096 + c * 64) * 128;
    const int t = threadIdx.x, lane = t & 63, w = t >> 6;
    const int l15 = lane & 15, kg = (lane >> 4) * 8, rbase = (lane >> 4) * 4;

    for (int i = t; i < 64 * 48; i += 256) {
        const int row = i / 48, c4 = (i % 48) * 4;
        ushort4 kv4 = *(const ushort4*)(Kc + (size_t)row * 192 + c4);
        lkt[c4 + 0][row] = (short)kv4.x;
        lkt[c4 + 1][row] = (short)kv4.y;
        lkt[c4 + 2][row] = (short)kv4.z;
        lkt[c4 + 3][row] = (short)kv4.w;
    }
    for (int i = t; i < 64 * 32; i += 256) {
        const int row = i >> 5, c4 = (i & 31) * 4;
        ushort4 vv = *(const ushort4*)(Vc + (size_t)row * 128 + c4);
        lvt[c4 + 0][row] = (short)vv.x;
        lvt[c4 + 1][row] = (short)vv.y;
        lvt[c4 + 2][row] = (short)vv.z;
        lvt[c4 + 3][row] = (short)vv.w;
    }
    __syncthreads();

    f32x4 acc[2][12];
#pragma unroll
    for (int i = 0; i < 2; ++i)
#pragma unroll
        for (int j = 0; j < 12; ++j) acc[i][j] = (f32x4){0.f, 0.f, 0.f, 0.f};
#pragma unroll
    for (int ks = 0; ks < 2; ++ks) {
        bf16x8 af[2];
#pragma unroll
        for (int i = 0; i < 2; ++i) af[i] = *(const bf16x8*)&lvt[w * 32 + i * 16 + l15][ks * 32 + kg];
#pragma unroll
        for (int j = 0; j < 12; ++j) {
            const bf16x8 bk = *(const bf16x8*)&lkt[j * 16 + l15][ks * 32 + kg];
#pragma unroll
            for (int i = 0; i < 2; ++i) acc[i][j] = MFMA16(af[i], bk, acc[i][j]);
        }
    }
    __syncthreads();
#pragma unroll
    for (int i = 0; i < 2; ++i)
#pragma unroll
        for (int j = 0; j < 12; ++j)
#pragma unroll
            for (int q = 0; q < 4; ++q)
                outT[w * 32 + i * 16 + rbase + q][j * 16 + l15] = f2bf(acc[i][j][q]);
    __syncthreads();

    short* kvp = kvcT + ((size_t)bh * 64 + c) * 24576;
    for (int i = t; i < 3072; i += 256) {
        const int s8 = i * 8;
        const int row = s8 / 192, col = s8 % 192;
        *(u16x8*)(kvp + s8) = *(const u16x8*)&outT[row][col];
    }
}

// ---------- exclusive cumsum over chunks (bf16 in-place) + initT ----------
__global__ __launch_bounds__(256) void ssa_scan(
    short* __restrict__ kvc, const float* __restrict__ initT)
{
    const int bh = blockIdx.y;
    const int e8 = (blockIdx.x * 256 + threadIdx.x) * 8;
    float st[8];
    {
        const float4 i0 = *(const float4*)(initT + (size_t)bh * 24576 + e8);
        const float4 i1 = *(const float4*)(initT + (size_t)bh * 24576 + e8 + 4);
        st[0] = i0.x; st[1] = i0.y; st[2] = i0.z; st[3] = i0.w;
        st[4] = i1.x; st[5] = i1.y; st[6] = i1.z; st[7] = i1.w;
    }
    short* p = kvc + (size_t)bh * 64 * 24576 + e8;
    for (int cc = 0; cc < 64; ++cc) {
        const u16x8 v = *(const u16x8*)p;
        u16x8 o;
#pragma unroll
        for (int j = 0; j < 8; ++j) o[j] = (unsigned short)f2bf(st[j]);
        *(u16x8*)p = o;
#pragma unroll
        for (int j = 0; j < 8; ++j) st[j] += bf2f(v[j]);
        p += 24576;
    }
}

// ---------- fused: sc=tril(QK^T); attn=(sc@V + Q@state)*SCALE ----------
__global__ __launch_bounds__(256, 2) void ssa_out(
    const short* __restrict__ q_ssa, const short* __restrict__ k_ssa,
    const short* __restrict__ v_ssa, const short* __restrict__ states,
    short* __restrict__ attnb)
{
    __shared__ short lk[64][200];
    __shared__ short lvt[128][72];
    __shared__ short lst[128][104];
    __shared__ short lsc[64][72];
    const int c = blockIdx.x, h = blockIdx.y, b = blockIdx.z;
    const int bh = b * 16 + h;
    const short* Qb = q_ssa + ((size_t)bh * 4096 + c * 64) * 192;
    const short* Kc = k_ssa + ((size_t)bh * 4096 + c * 64) * 192;
    const short* Vc = v_ssa + ((size_t)bh * 4096 + c * 64) * 128;
    const short* st = states + ((size_t)bh * 64 + c) * 24576;
    const int t = threadIdx.x, lane = t & 63, w = t >> 6;
    const int l15 = lane & 15, kg = (lane >> 4) * 8, rbase = (lane >> 4) * 4;

    // Q fragments in registers (wave-exclusive rows)
    bf16x8 aq[6];
    {
        const short* Qr = Qb + (size_t)(w * 16 + l15) * 192 + kg;
#pragma unroll
        for (int ks = 0; ks < 6; ++ks) aq[ks] = *(const bf16x8*)(Qr + ks * 32);
    }
    // stage K rows (vector), V transposed (scalar), state half-0
    for (int i = t; i < 1536; i += 256) {
        const int row = i / 24, c8 = (i % 24) * 8;
        *(u16x8*)&lk[row][c8] = *(const u16x8*)(Kc + (size_t)row * 192 + c8);
    }
    for (int i = t; i < 2048; i += 256) {
        const int row = i >> 5, c4 = (i & 31) * 4;
        ushort4 vv = *(const ushort4*)(Vc + (size_t)row * 128 + c4);
        lvt[c4 + 0][row] = (short)vv.x;
        lvt[c4 + 1][row] = (short)vv.y;
        lvt[c4 + 2][row] = (short)vv.z;
        lvt[c4 + 3][row] = (short)vv.w;
    }
    for (int i = t; i < 1536; i += 256) {
        const int row = i / 12, c8 = (i % 12) * 8;
        *(u16x8*)&lst[row][c8] = *(const u16x8*)(st + (size_t)row * 192 + c8);
    }
    __syncthreads();

    // sc = tril(Q K^T)
    {
        f32x4 sc[4];
#pragma unroll
        for (int j = 0; j < 4; ++j) sc[j] = (f32x4){0.f, 0.f, 0.f, 0.f};
#pragma unroll
        for (int ks = 0; ks < 6; ++ks)
#pragma unroll
            for (int j = 0; j < 4; ++j) {
                const bf16x8 bk = *(const bf16x8*)&lk[j * 16 + l15][ks * 32 + kg];
                sc[j] = MFMA16(aq[ks], bk, sc[j]);
            }
#pragma unroll
        for (int j = 0; j < 4; ++j)
#pragma unroll
            for (int q = 0; q < 4; ++q) {
                const int l = w * 16 + rbase + q;
                const int m = j * 16 + l15;
                lsc[l][m] = f2bf((m <= l) ? sc[j][q] : 0.f);
            }
    }
    __syncthreads();

    f32x4 acc[8];
#pragma unroll
    for (int j = 0; j < 8; ++j) acc[j] = (f32x4){0.f, 0.f, 0.f, 0.f};
    // intra = sc @ V
#pragma unroll
    for (int ks = 0; ks < 2; ++ks) {
        const bf16x8 as = *(const bf16x8*)&lsc[w * 16 + l15][ks * 32 + kg];
#pragma unroll
        for (int j = 0; j < 8; ++j) {
            const bf16x8 bv = *(const bf16x8*)&lvt[j * 16 + l15][ks * 32 + kg];
            acc[j] = MFMA16(as, bv, acc[j]);
        }
    }
    // inter, dk 0..95
#pragma unroll
    for (int ks = 0; ks < 3; ++ks)
#pragma unroll
        for (int j = 0; j < 8; ++j) {
            const bf16x8 bs = *(const bf16x8*)&lst[j * 16 + l15][ks * 32 + kg];
            acc[j] = MFMA16(aq[ks], bs, acc[j]);
        }
    __syncthreads();
    // restage state half-1 (dk 96..191)
    for (int i = t; i < 1536; i += 256) {
        const int row = i / 12, c8 = (i % 12) * 8;
        *(u16x8*)&lst[row][c8] = *(const u16x8*)(st + (size_t)row * 192 + 96 + c8);
    }
    __syncthreads();
#pragma unroll
    for (int ks = 3; ks < 6; ++ks)
#pragma unroll
        for (int j = 0; j < 8; ++j) {
            const bf16x8 bs = *(const bf16x8*)&lst[j * 16 + l15][(ks - 3) * 32 + kg];
            acc[j] = MFMA16(aq[ks], bs, acc[j]);
        }

    const float scale = 0.07216878364870322f;  // 192^-0.5
#pragma unroll
    for (int j = 0; j < 8; ++j)
#pragma unroll
        for (int q = 0; q < 4; ++q) {
            const int l = w * 16 + rbase + q;
            const int dv = j * 16 + l15;
            attnb[((size_t)(b * 4096 + c * 64 + l)) * 2048 + h * 128 + dv] = f2bf(acc[j][q] * scale);
        }
}

// ---------- launch ----------
extern "C" void kernel_launch(void* const* d_in, const int* in_sizes, int n_in,
                              void* d_out, int out_size, void* d_ws, size_t ws_size,
                              hipStream_t stream) {
    const float* x     = (const float*)d_in[0];
    const float* cosT  = (const float*)d_in[2];
    const float* sinT  = (const float*)d_in[3];
    const float* wq_a  = (const float*)d_in[4];
    const float* wq_b  = (const float*)d_in[5];
    const float* wkv_a = (const float*)d_in[6];
    const float* wkv_b = (const float*)d_in[7];
    const float* wo    = (const float*)d_in[8];
    const float* qw    = (const float*)d_in[9];
    const float* kvw   = (const float*)d_in[10];
    const float* init  = (const float*)d_in[11];
    float* out = (float*)d_out;

    void* base = nullptr;
    hipGetSymbolAddress(&base, HIP_SYMBOL(g_ws));
    char* ws = (char*)base;
    size_t off = 0;
    auto take = [&](size_t bytes) -> char* {
        char* p = ws + off;
        off += (bytes + 255) & ~(size_t)255;
        return p;
    };
    short* xb    = (short*)take((size_t)8192 * 2048 * 2);
    short* wab   = (short*)take((size_t)1152 * 2048 * 2);
    short* wqbb  = (short*)take((size_t)3072 * 512 * 2);
    short* wkvbb = (short*)take((size_t)4096 * 512 * 2);
    short* wob   = (short*)take((size_t)2048 * 2048 * 2);
    short* y1b   = (short*)take((size_t)8192 * 1088 * 2);
    short* qnb   = (short*)take((size_t)8192 * 512 * 2);
    short* kvnb  = (short*)take((size_t)8192 * 512 * 2);
    float* kpe   = (float*)take((size_t)8192 * 64 * 4);
    short* qbig  = (short*)take((size_t)8192 * 3072 * 2);
    short* kvbig = (short*)take((size_t)8192 * 4096 * 2);
    short* qs    = (short*)take((size_t)2 * 16 * 4096 * 192 * 2);
    short* ksb   = (short*)take((size_t)2 * 16 * 4096 * 192 * 2);
    short* vsb   = (short*)take((size_t)2 * 16 * 4096 * 128 * 2);
    short* kvcT  = (short*)take((size_t)2048 * 24576 * 2);
    float* initT = (float*)take((size_t)32 * 24576 * 4);
    short* attnb = (short*)take((size_t)8192 * 2048 * 2);

    // 0. convert inputs/weights to bf16; transpose init
    cvt_bf16<<<(8192 * 2048 / 4 + 255) / 256, 256, 0, stream>>>(x, xb, 8192 * 2048);
    cvt_bf16<<<(512 * 2048 / 4 + 255) / 256, 256, 0, stream>>>(wq_a, wab, 512 * 2048);
    cvt_bf16<<<(576 * 2048 / 4 + 255) / 256, 256, 0, stream>>>(wkv_a, wab + (size_t)512 * 2048, 576 * 2048);
    hipMemsetAsync(wab + (size_t)1088 * 2048, 0, (size_t)64 * 2048 * 2, stream);
    cvt_bf16<<<(3072 * 512 / 4 + 255) / 256, 256, 0, stream>>>(wq_b, wqbb, 3072 * 512);
    cvt_bf16<<<(4096 * 512 / 4 + 255) / 256, 256, 0, stream>>>(wkv_b, wkvbb, 4096 * 512);
    cvt_bf16<<<(2048 * 2048 / 4 + 255) / 256, 256, 0, stream>>>(wo, wob, 2048 * 2048);
    init_t_kern<<<dim3(24, 32), 256, 0, stream>>>(init, initT);

    // 1. Y1 = x @ [wq_a; wkv_a]^T
    gemm_lds<1><<<dim3(64, 9), 256, 0, stream>>>(xb, 2048, wab, 2048, y1b, 1088, 1088, 2048);
    // 2. RMSNorm + rope(k_pe)
    rms_rope<<<8192, 256, 0, stream>>>(y1b, qw, kvw, cosT, sinT, qnb, kvnb, kpe);
    // 3a. q = qn @ wq_b^T
    gemm_lds<1><<<dim3(64, 24), 256, 0, stream>>>(qnb, 512, wqbb, 512, qbig, 3072, 3072, 512);
    build_q<<<8192, 192, 0, stream>>>(qbig, cosT, sinT, qs);
    // 3b. kv = kvn @ wkv_b^T
    gemm_lds<1><<<dim3(64, 32), 256, 0, stream>>>(kvnb, 512, wkvbb, 512, kvbig, 4096, 4096, 512);
    build_kv<<<8192, 256, 0, stream>>>(kvbig, kpe, ksb, vsb);
    // 4. SSA
    ssa_kv<<<dim3(64, 16, 2), 256, 0, stream>>>(ksb, vsb, kvcT);
    ssa_scan<<<dim3(12, 32), 256, 0, stream>>>(kvcT, initT);
    ssa_out<<<dim3(64, 16, 2), 256, 0, stream>>>(qs, ksb, vsb, kvcT, attnb);
    // 5. out = attn @ wo^T (fp32 out)
    gemm_lds<0><<<dim3(64, 16), 256, 0, stream>>>(attnb, 2048, wob, 2048, out, 2048, 2048, 2048);
}

// Round 5
// 641.035 us; speedup vs baseline: 2.0410x; 1.0744x over previous
//
#include <hip/hip_runtime.h>

// ---------- static device workspace ----------
static __device__ __align__(256) unsigned char g_ws[645200000];

// ---------- types ----------
typedef __attribute__((ext_vector_type(8))) __bf16 bf16x8;
typedef __attribute__((ext_vector_type(4))) float  f32x4;
typedef __attribute__((ext_vector_type(8))) unsigned short u16x8;

__device__ __forceinline__ short f2bf(float f) {
    union { float f; unsigned u; } v; v.f = f;
    unsigned r = v.u + 0x7FFFu + ((v.u >> 16) & 1u);
    return (short)(r >> 16);
}
__device__ __forceinline__ float bf2f(unsigned short u) {
    union { unsigned u; float f; } v; v.u = ((unsigned)u) << 16;
    return v.f;
}
__device__ __forceinline__ float elu1(float x) {
    return x > 0.f ? x + 1.f : __expf(x);
}
__device__ __forceinline__ void gload_lds16(const void* g, void* l) {
    __builtin_amdgcn_global_load_lds(
        (const __attribute__((address_space(1))) unsigned int*)g,
        (__attribute__((address_space(3))) unsigned int*)l, 16, 0, 0);
}

#define MFMA16(a, b, c) __builtin_amdgcn_mfma_f32_16x16x32_bf16((a), (b), (c), 0, 0, 0)

// ---------- fp32 -> bf16 convert ----------
__global__ __launch_bounds__(256) void cvt_bf16(
    const float* __restrict__ src, short* __restrict__ dst, int n)
{
    const int i = (blockIdx.x * 256 + threadIdx.x) * 4;
    if (i < n) {
        const float4 v = *(const float4*)(src + i);
        ushort4 o;
        o.x = (unsigned short)f2bf(v.x);
        o.y = (unsigned short)f2bf(v.y);
        o.z = (unsigned short)f2bf(v.z);
        o.w = (unsigned short)f2bf(v.w);
        *(ushort4*)(dst + i) = o;
    }
}

// ---------- GEMM 256x256, BK=32, 4-deep counted-vmcnt pipeline ----------
// C[m][n] = sum_k A[m][k]*Bt[n][k].  A bf16 [M][lda], Bt bf16 [Npad][ldb].
// grid = 1-D (M/256)*(Npad/256), 512 threads. K mult of 32, K>=96.
// LDS swizzle: linear gload_lds dest; source col byte ^= ((row>>2)&3)<<4;
// frag read applies same XOR -> 2-way conflicts (free).
template <int OUT_BF16>
__global__ __launch_bounds__(512, 2) void gemm256(
    const short* __restrict__ A, int lda,
    const short* __restrict__ Bt, int ldb,
    void* __restrict__ Cv, int ldc,
    int Nvalid, int K, int nbx)
{
    __shared__ short lds[65536];   // 128 KiB: A slots [0,64K), B slots [64K,128K)
    char* ldsB = (char*)lds;
    const int t = threadIdx.x;
    const int lane = t & 63, w = t >> 6;

    // bijective XCD swizzle (grid % 8 == 0 at all call sites)
    const int cpx = gridDim.x >> 3;
    const int id = (blockIdx.x & 7) * cpx + (blockIdx.x >> 3);
    const int row0 = (id % nbx) * 256;
    const int col0 = (id / nbx) * 256;

    // staging geometry: wave w stages rows [w*32, w*32+32) of each tile.
    const int r_in = lane >> 2;                                   // 0..15
    const int sw_src = ((lane & 3) << 4) ^ (((lane >> 4) & 3) << 4);
    const char* aSrc = (const char*)A + ((size_t)(row0 + w * 32 + r_in) * lda) * 2 + sw_src;
    const char* bSrc = (const char*)Bt + ((size_t)(col0 + w * 32 + r_in) * ldb) * 2 + sw_src;
    const size_t aStep = (size_t)lda * 32;   // 16 rows, bytes
    const size_t bStep = (size_t)ldb * 32;
    char* aDst = ldsB + (w * 2) * 1024 + lane * 16;
    char* bDst = ldsB + 65536 + (w * 2) * 1024 + lane * 16;

    // compute geometry: wave grid 2(M)x4(N); per-wave output 128x64
    const int wr = (w >> 2) * 128, wc = (w & 3) * 64;
    const int l15 = lane & 15;
    const int kxor = ((lane >> 4) * 16) ^ (((l15 >> 2) & 3) << 4);  // byte offset in 64B row

    const int NT = K >> 5;

    auto STAGE = [&](int j) {
        const int sb = (j & 3) * 16384;
        const size_t kb = (size_t)j * 64;
        gload_lds16(aSrc + kb,         aDst + sb);
        gload_lds16(aSrc + kb + aStep, aDst + sb + 1024);
        gload_lds16(bSrc + kb,         bDst + sb);
        gload_lds16(bSrc + kb + bStep, bDst + sb + 1024);
    };

    f32x4 acc[8][4];
#pragma unroll
    for (int i = 0; i < 8; ++i)
#pragma unroll
        for (int j = 0; j < 4; ++j) acc[i][j] = (f32x4){0.f, 0.f, 0.f, 0.f};

    STAGE(0); STAGE(1); STAGE(2);

#pragma unroll 1
    for (int kt = 0; kt < NT; ++kt) {
        if (kt < NT - 2)        asm volatile("s_waitcnt vmcnt(8)" ::: "memory");
        else if (kt == NT - 2)  asm volatile("s_waitcnt vmcnt(4)" ::: "memory");
        else                    asm volatile("s_waitcnt vmcnt(0)" ::: "memory");
        __builtin_amdgcn_s_barrier();
        __builtin_amdgcn_sched_barrier(0);
        if (kt + 3 < NT) STAGE(kt + 3);
        const char* aS = ldsB + (kt & 3) * 16384;
        const char* bS = ldsB + 65536 + (kt & 3) * 16384;
        bf16x8 af[8], bf4[4];
#pragma unroll
        for (int i = 0; i < 8; ++i)
            af[i] = *(const bf16x8*)(aS + (wr + i * 16 + l15) * 64 + kxor);
#pragma unroll
        for (int j = 0; j < 4; ++j)
            bf4[j] = *(const bf16x8*)(bS + (wc + j * 16 + l15) * 64 + kxor);
        __builtin_amdgcn_s_setprio(1);
#pragma unroll
        for (int i = 0; i < 8; ++i)
#pragma unroll
            for (int j = 0; j < 4; ++j)
                acc[i][j] = MFMA16(af[i], bf4[j], acc[i][j]);
        __builtin_amdgcn_s_setprio(0);
    }

    const int rbase = (lane >> 4) * 4;
#pragma unroll
    for (int i = 0; i < 8; ++i)
#pragma unroll
        for (int j = 0; j < 4; ++j) {
            const int cc = col0 + wc + j * 16 + l15;
            if (cc < Nvalid) {
#pragma unroll
                for (int q = 0; q < 4; ++q) {
                    const size_t o = (size_t)(row0 + wr + i * 16 + rbase + q) * ldc + cc;
                    if (OUT_BF16) ((short*)Cv)[o] = f2bf(acc[i][j][q]);
                    else          ((float*)Cv)[o] = acc[i][j][q];
                }
            }
        }
}

// ---------- RMSNorm (q-lat, kv-lat) + RoPE on k_pe ----------
__global__ __launch_bounds__(256) void rms_rope(
    const short* __restrict__ Y1,
    const float* __restrict__ qw, const float* __restrict__ kvw,
    const float* __restrict__ cosT, const float* __restrict__ sinT,
    short* __restrict__ qn, short* __restrict__ kvn, float* __restrict__ kpe)
{
    __shared__ float red[256];
    const int row = blockIdx.x;
    const int s = row & 4095;
    const int t = threadIdx.x;
    const unsigned short* yr = (const unsigned short*)(Y1 + (size_t)row * 1088);

    float v0 = bf2f(yr[t]), v1 = bf2f(yr[t + 256]);
    red[t] = v0 * v0 + v1 * v1;
    __syncthreads();
    for (int off = 128; off > 0; off >>= 1) {
        if (t < off) red[t] += red[t + off];
        __syncthreads();
    }
    float rs = rsqrtf(red[0] / 512.f + 1e-6f);
    __syncthreads();
    qn[(size_t)row * 512 + t]       = f2bf(v0 * rs * qw[t]);
    qn[(size_t)row * 512 + t + 256] = f2bf(v1 * rs * qw[t + 256]);

    float u0 = bf2f(yr[512 + t]), u1 = bf2f(yr[768 + t]);
    red[t] = u0 * u0 + u1 * u1;
    __syncthreads();
    for (int off = 128; off > 0; off >>= 1) {
        if (t < off) red[t] += red[t + off];
        __syncthreads();
    }
    float rs2 = rsqrtf(red[0] / 512.f + 1e-6f);
    kvn[(size_t)row * 512 + t]       = f2bf(u0 * rs2 * kvw[t]);
    kvn[(size_t)row * 512 + t + 256] = f2bf(u1 * rs2 * kvw[t + 256]);

    if (t < 32) {
        float xr = bf2f(yr[1024 + 2 * t]), xi = bf2f(yr[1024 + 2 * t + 1]);
        float cc = cosT[(size_t)s * 32 + t], sn = sinT[(size_t)s * 32 + t];
        kpe[(size_t)row * 64 + 2 * t]     = xr * cc - xi * sn;
        kpe[(size_t)row * 64 + 2 * t + 1] = xr * sn + xi * cc;
    }
}

// ---------- build q_ssa ----------
__global__ __launch_bounds__(192) void build_q(
    const short* __restrict__ qbig,
    const float* __restrict__ cosT, const float* __restrict__ sinT,
    short* __restrict__ q_ssa)
{
    const int row = blockIdx.x;
    const int s = row & 4095;
    const int b = row >> 12;
    const int d = threadIdx.x;
    const unsigned short* qr = (const unsigned short*)(qbig + (size_t)row * 3072);
#pragma unroll 1
    for (int h = 0; h < 16; ++h) {
        float val;
        if (d < 128) {
            val = bf2f(qr[h * 192 + d]);
        } else {
            const int p = (d - 128) >> 1;
            const float xr = bf2f(qr[h * 192 + 128 + 2 * p]);
            const float xi = bf2f(qr[h * 192 + 128 + 2 * p + 1]);
            const float cc = cosT[(size_t)s * 32 + p];
            const float sn = sinT[(size_t)s * 32 + p];
            val = ((d & 1) == 0) ? (xr * cc - xi * sn) : (xr * sn + xi * cc);
        }
        val = elu1(val);
        q_ssa[((size_t)(b * 16 + h) * 4096 + s) * 192 + d] = f2bf(val);
    }
}

// ---------- build k_ssa / v_ssa ----------
__global__ __launch_bounds__(256) void build_kv(
    const short* __restrict__ kvbig, const float* __restrict__ kpe,
    short* __restrict__ k_ssa, short* __restrict__ v_ssa)
{
    const int row = blockIdx.x;
    const int s = row & 4095;
    const int b = row >> 12;
    const int t = threadIdx.x;
    const unsigned short* kr = (const unsigned short*)(kvbig + (size_t)row * 4096);
    const float* pe = kpe + (size_t)row * 64;
#pragma unroll 1
    for (int h = 0; h < 16; ++h) {
        const size_t kbase = ((size_t)(b * 16 + h) * 4096 + s) * 192;
        const size_t vbase = ((size_t)(b * 16 + h) * 4096 + s) * 128;
        if (t < 128) {
            k_ssa[kbase + t] = f2bf(elu1(bf2f(kr[h * 256 + t])));
            v_ssa[vbase + t] = (short)kr[h * 256 + 128 + t];
        } else if (t < 192) {
            const int d = t - 128;
            k_ssa[kbase + 128 + d] = f2bf(elu1(pe[d]));
        }
    }
}

// ---------- transpose init_state [bh][dk][dv] -> [bh][dv][dk] ----------
__global__ __launch_bounds__(256) void init_t_kern(
    const float* __restrict__ init, float* __restrict__ initT)
{
    __shared__ float tile[32][33];
    const int bh = blockIdx.y;
    const int tk = blockIdx.x % 6, tv = blockIdx.x / 6;
    const int r0 = threadIdx.x >> 5, c = threadIdx.x & 31;
    const float* src = init + (size_t)bh * 24576;
    float* dst = initT + (size_t)bh * 24576;
#pragma unroll
    for (int p = 0; p < 4; ++p) {
        const int rr = r0 + 8 * p;
        tile[rr][c] = src[(size_t)(tk * 32 + rr) * 128 + tv * 32 + c];
    }
    __syncthreads();
#pragma unroll
    for (int p = 0; p < 4; ++p) {
        const int rr = r0 + 8 * p;
        dst[(size_t)(tv * 32 + rr) * 192 + tk * 32 + c] = tile[c][rr];
    }
}

// ---------- per-chunk kv^T = V^T K, bf16 transposed output [dv][dk] ----------
__global__ __launch_bounds__(256, 3) void ssa_kv(
    const short* __restrict__ k_ssa, const short* __restrict__ v_ssa,
    short* __restrict__ kvcT)
{
    __shared__ short smem[25600];                    // 51200 B
    short (*lkt)[72] = (short(*)[72])smem;           // [192][72]
    short (*lvt)[72] = (short(*)[72])(smem + 192 * 72);  // [128][72]
    short (*outT)[200] = (short(*)[200])smem;        // [128][200] (alias)
    const int c = blockIdx.x, h = blockIdx.y, b = blockIdx.z;
    const int bh = b * 16 + h;
    const short* Kc = k_ssa + ((size_t)bh * 4096 + c * 64) * 192;
    const short* Vc = v_ssa + ((size_t)bh * 4096 + c * 64) * 128;
    const int t = threadIdx.x, lane = t & 63, w = t >> 6;
    const int l15 = lane & 15, kg = (lane >> 4) * 8, rbase = (lane >> 4) * 4;

    for (int i = t; i < 64 * 48; i += 256) {
        const int row = i / 48, c4 = (i % 48) * 4;
        ushort4 kv4 = *(const ushort4*)(Kc + (size_t)row * 192 + c4);
        lkt[c4 + 0][row] = (short)kv4.x;
        lkt[c4 + 1][row] = (short)kv4.y;
        lkt[c4 + 2][row] = (short)kv4.z;
        lkt[c4 + 3][row] = (short)kv4.w;
    }
    for (int i = t; i < 64 * 32; i += 256) {
        const int row = i >> 5, c4 = (i & 31) * 4;
        ushort4 vv = *(const ushort4*)(Vc + (size_t)row * 128 + c4);
        lvt[c4 + 0][row] = (short)vv.x;
        lvt[c4 + 1][row] = (short)vv.y;
        lvt[c4 + 2][row] = (short)vv.z;
        lvt[c4 + 3][row] = (short)vv.w;
    }
    __syncthreads();

    f32x4 acc[2][12];
#pragma unroll
    for (int i = 0; i < 2; ++i)
#pragma unroll
        for (int j = 0; j < 12; ++j) acc[i][j] = (f32x4){0.f, 0.f, 0.f, 0.f};
#pragma unroll
    for (int ks = 0; ks < 2; ++ks) {
        bf16x8 af[2];
#pragma unroll
        for (int i = 0; i < 2; ++i) af[i] = *(const bf16x8*)&lvt[w * 32 + i * 16 + l15][ks * 32 + kg];
#pragma unroll
        for (int j = 0; j < 12; ++j) {
            const bf16x8 bk = *(const bf16x8*)&lkt[j * 16 + l15][ks * 32 + kg];
#pragma unroll
            for (int i = 0; i < 2; ++i) acc[i][j] = MFMA16(af[i], bk, acc[i][j]);
        }
    }
    __syncthreads();
#pragma unroll
    for (int i = 0; i < 2; ++i)
#pragma unroll
        for (int j = 0; j < 12; ++j)
#pragma unroll
            for (int q = 0; q < 4; ++q)
                outT[w * 32 + i * 16 + rbase + q][j * 16 + l15] = f2bf(acc[i][j][q]);
    __syncthreads();

    short* kvp = kvcT + ((size_t)bh * 64 + c) * 24576;
    for (int i = t; i < 3072; i += 256) {
        const int s8 = i * 8;
        const int row = s8 / 192, col = s8 % 192;
        *(u16x8*)(kvp + s8) = *(const u16x8*)&outT[row][col];
    }
}

// ---------- exclusive cumsum over chunks (bf16 in-place) + initT ----------
__global__ __launch_bounds__(256) void ssa_scan(
    short* __restrict__ kvc, const float* __restrict__ initT)
{
    const int bh = blockIdx.y;
    const int e8 = (blockIdx.x * 256 + threadIdx.x) * 8;
    float st[8];
    {
        const float4 i0 = *(const float4*)(initT + (size_t)bh * 24576 + e8);
        const float4 i1 = *(const float4*)(initT + (size_t)bh * 24576 + e8 + 4);
        st[0] = i0.x; st[1] = i0.y; st[2] = i0.z; st[3] = i0.w;
        st[4] = i1.x; st[5] = i1.y; st[6] = i1.z; st[7] = i1.w;
    }
    short* p = kvc + (size_t)bh * 64 * 24576 + e8;
    for (int cc = 0; cc < 64; ++cc) {
        const u16x8 v = *(const u16x8*)p;
        u16x8 o;
#pragma unroll
        for (int j = 0; j < 8; ++j) o[j] = (unsigned short)f2bf(st[j]);
        *(u16x8*)p = o;
#pragma unroll
        for (int j = 0; j < 8; ++j) st[j] += bf2f(v[j]);
        p += 24576;
    }
}

// ---------- fused: sc=tril(QK^T); attn=(sc@V + Q@state)*SCALE ----------
__global__ __launch_bounds__(256, 2) void ssa_out(
    const short* __restrict__ q_ssa, const short* __restrict__ k_ssa,
    const short* __restrict__ v_ssa, const short* __restrict__ states,
    short* __restrict__ attnb)
{
    __shared__ short lk[64][200];
    __shared__ short lvt[128][72];
    __shared__ short lst[128][104];
    __shared__ short lsc[64][72];
    const int c = blockIdx.x, h = blockIdx.y, b = blockIdx.z;
    const int bh = b * 16 + h;
    const short* Qb = q_ssa + ((size_t)bh * 4096 + c * 64) * 192;
    const short* Kc = k_ssa + ((size_t)bh * 4096 + c * 64) * 192;
    const short* Vc = v_ssa + ((size_t)bh * 4096 + c * 64) * 128;
    const short* st = states + ((size_t)bh * 64 + c) * 24576;
    const int t = threadIdx.x, lane = t & 63, w = t >> 6;
    const int l15 = lane & 15, kg = (lane >> 4) * 8, rbase = (lane >> 4) * 4;

    bf16x8 aq[6];
    {
        const short* Qr = Qb + (size_t)(w * 16 + l15) * 192 + kg;
#pragma unroll
        for (int ks = 0; ks < 6; ++ks) aq[ks] = *(const bf16x8*)(Qr + ks * 32);
    }
    for (int i = t; i < 1536; i += 256) {
        const int row = i / 24, c8 = (i % 24) * 8;
        *(u16x8*)&lk[row][c8] = *(const u16x8*)(Kc + (size_t)row * 192 + c8);
    }
    for (int i = t; i < 2048; i += 256) {
        const int row = i >> 5, c4 = (i & 31) * 4;
        ushort4 vv = *(const ushort4*)(Vc + (size_t)row * 128 + c4);
        lvt[c4 + 0][row] = (short)vv.x;
        lvt[c4 + 1][row] = (short)vv.y;
        lvt[c4 + 2][row] = (short)vv.z;
        lvt[c4 + 3][row] = (short)vv.w;
    }
    for (int i = t; i < 1536; i += 256) {
        const int row = i / 12, c8 = (i % 12) * 8;
        *(u16x8*)&lst[row][c8] = *(const u16x8*)(st + (size_t)row * 192 + c8);
    }
    __syncthreads();

    {
        f32x4 sc[4];
#pragma unroll
        for (int j = 0; j < 4; ++j) sc[j] = (f32x4){0.f, 0.f, 0.f, 0.f};
#pragma unroll
        for (int ks = 0; ks < 6; ++ks)
#pragma unroll
            for (int j = 0; j < 4; ++j) {
                const bf16x8 bk = *(const bf16x8*)&lk[j * 16 + l15][ks * 32 + kg];
                sc[j] = MFMA16(aq[ks], bk, sc[j]);
            }
#pragma unroll
        for (int j = 0; j < 4; ++j)
#pragma unroll
            for (int q = 0; q < 4; ++q) {
                const int l = w * 16 + rbase + q;
                const int m = j * 16 + l15;
                lsc[l][m] = f2bf((m <= l) ? sc[j][q] : 0.f);
            }
    }
    __syncthreads();

    f32x4 acc[8];
#pragma unroll
    for (int j = 0; j < 8; ++j) acc[j] = (f32x4){0.f, 0.f, 0.f, 0.f};
#pragma unroll
    for (int ks = 0; ks < 2; ++ks) {
        const bf16x8 as = *(const bf16x8*)&lsc[w * 16 + l15][ks * 32 + kg];
#pragma unroll
        for (int j = 0; j < 8; ++j) {
            const bf16x8 bv = *(const bf16x8*)&lvt[j * 16 + l15][ks * 32 + kg];
            acc[j] = MFMA16(as, bv, acc[j]);
        }
    }
#pragma unroll
    for (int ks = 0; ks < 3; ++ks)
#pragma unroll
        for (int j = 0; j < 8; ++j) {
            const bf16x8 bs = *(const bf16x8*)&lst[j * 16 + l15][ks * 32 + kg];
            acc[j] = MFMA16(aq[ks], bs, acc[j]);
        }
    __syncthreads();
    for (int i = t; i < 1536; i += 256) {
        const int row = i / 12, c8 = (i % 12) * 8;
        *(u16x8*)&lst[row][c8] = *(const u16x8*)(st + (size_t)row * 192 + 96 + c8);
    }
    __syncthreads();
#pragma unroll
    for (int ks = 3; ks < 6; ++ks)
#pragma unroll
        for (int j = 0; j < 8; ++j) {
            const bf16x8 bs = *(const bf16x8*)&lst[j * 16 + l15][(ks - 3) * 32 + kg];
            acc[j] = MFMA16(aq[ks], bs, acc[j]);
        }

    const float scale = 0.07216878364870322f;  // 192^-0.5
#pragma unroll
    for (int j = 0; j < 8; ++j)
#pragma unroll
        for (int q = 0; q < 4; ++q) {
            const int l = w * 16 + rbase + q;
            const int dv = j * 16 + l15;
            attnb[((size_t)(b * 4096 + c * 64 + l)) * 2048 + h * 128 + dv] = f2bf(acc[j][q] * scale);
        }
}

// ---------- launch ----------
extern "C" void kernel_launch(void* const* d_in, const int* in_sizes, int n_in,
                              void* d_out, int out_size, void* d_ws, size_t ws_size,
                              hipStream_t stream) {
    const float* x     = (const float*)d_in[0];
    const float* cosT  = (const float*)d_in[2];
    const float* sinT  = (const float*)d_in[3];
    const float* wq_a  = (const float*)d_in[4];
    const float* wq_b  = (const float*)d_in[5];
    const float* wkv_a = (const float*)d_in[6];
    const float* wkv_b = (const float*)d_in[7];
    const float* wo    = (const float*)d_in[8];
    const float* qw    = (const float*)d_in[9];
    const float* kvw   = (const float*)d_in[10];
    const float* init  = (const float*)d_in[11];
    float* out = (float*)d_out;

    void* base = nullptr;
    hipGetSymbolAddress(&base, HIP_SYMBOL(g_ws));
    char* ws = (char*)base;
    size_t off = 0;
    auto take = [&](size_t bytes) -> char* {
        char* p = ws + off;
        off += (bytes + 255) & ~(size_t)255;
        return p;
    };
    short* xb    = (short*)take((size_t)8192 * 2048 * 2);
    short* wab   = (short*)take((size_t)1280 * 2048 * 2);   // [wq_a;wkv_a;pad to 1280]
    short* wqbb  = (short*)take((size_t)3072 * 512 * 2);
    short* wkvbb = (short*)take((size_t)4096 * 512 * 2);
    short* wob   = (short*)take((size_t)2048 * 2048 * 2);
    short* y1b   = (short*)take((size_t)8192 * 1088 * 2);
    short* qnb   = (short*)take((size_t)8192 * 512 * 2);
    short* kvnb  = (short*)take((size_t)8192 * 512 * 2);
    float* kpe   = (float*)take((size_t)8192 * 64 * 4);
    short* qbig  = (short*)take((size_t)8192 * 3072 * 2);
    short* kvbig = (short*)take((size_t)8192 * 4096 * 2);
    short* qs    = (short*)take((size_t)2 * 16 * 4096 * 192 * 2);
    short* ksb   = (short*)take((size_t)2 * 16 * 4096 * 192 * 2);
    short* vsb   = (short*)take((size_t)2 * 16 * 4096 * 128 * 2);
    short* kvcT  = (short*)take((size_t)2048 * 24576 * 2);
    float* initT = (float*)take((size_t)32 * 24576 * 4);
    short* attnb = (short*)take((size_t)8192 * 2048 * 2);

    // 0. convert inputs/weights to bf16; transpose init
    cvt_bf16<<<(8192 * 2048 / 4 + 255) / 256, 256, 0, stream>>>(x, xb, 8192 * 2048);
    cvt_bf16<<<(512 * 2048 / 4 + 255) / 256, 256, 0, stream>>>(wq_a, wab, 512 * 2048);
    cvt_bf16<<<(576 * 2048 / 4 + 255) / 256, 256, 0, stream>>>(wkv_a, wab + (size_t)512 * 2048, 576 * 2048);
    hipMemsetAsync(wab + (size_t)1088 * 2048, 0, (size_t)192 * 2048 * 2, stream);
    cvt_bf16<<<(3072 * 512 / 4 + 255) / 256, 256, 0, stream>>>(wq_b, wqbb, 3072 * 512);
    cvt_bf16<<<(4096 * 512 / 4 + 255) / 256, 256, 0, stream>>>(wkv_b, wkvbb, 4096 * 512);
    cvt_bf16<<<(2048 * 2048 / 4 + 255) / 256, 256, 0, stream>>>(wo, wob, 2048 * 2048);
    init_t_kern<<<dim3(24, 32), 256, 0, stream>>>(init, initT);

    // 1. Y1 = x @ [wq_a; wkv_a]^T   (Npad=1280, Nvalid=1088)
    gemm256<1><<<160, 512, 0, stream>>>(xb, 2048, wab, 2048, y1b, 1088, 1088, 2048, 32);
    // 2. RMSNorm + rope(k_pe)
    rms_rope<<<8192, 256, 0, stream>>>(y1b, qw, kvw, cosT, sinT, qnb, kvnb, kpe);
    // 3a. q = qn @ wq_b^T
    gemm256<1><<<384, 512, 0, stream>>>(qnb, 512, wqbb, 512, qbig, 3072, 3072, 512, 32);
    build_q<<<8192, 192, 0, stream>>>(qbig, cosT, sinT, qs);
    // 3b. kv = kvn @ wkv_b^T
    gemm256<1><<<512, 512, 0, stream>>>(kvnb, 512, wkvbb, 512, kvbig, 4096, 4096, 512, 32);
    build_kv<<<8192, 256, 0, stream>>>(kvbig, kpe, ksb, vsb);
    // 4. SSA
    ssa_kv<<<dim3(64, 16, 2), 256, 0, stream>>>(ksb, vsb, kvcT);
    ssa_scan<<<dim3(12, 32), 256, 0, stream>>>(kvcT, initT);
    ssa_out<<<dim3(64, 16, 2), 256, 0, stream>>>(qs, ksb, vsb, kvcT, attnb);
    // 5. out = attn @ wo^T (fp32 out)
    gemm256<0><<<256, 512, 0, stream>>>(attnb, 2048, wob, 2048, out, 2048, 2048, 2048, 32);
}

// Round 6
// 623.151 us; speedup vs baseline: 2.0996x; 1.0287x over previous
//
#include <hip/hip_runtime.h>

// ---------- static device workspace ----------
static __device__ __align__(256) unsigned char g_ws[645200000];

// ---------- types ----------
typedef __attribute__((ext_vector_type(8))) __bf16 bf16x8;
typedef __attribute__((ext_vector_type(4))) float  f32x4;
typedef __attribute__((ext_vector_type(8))) unsigned short u16x8;

__device__ __forceinline__ short f2bf(float f) {
    union { float f; unsigned u; } v; v.f = f;
    unsigned r = v.u + 0x7FFFu + ((v.u >> 16) & 1u);
    return (short)(r >> 16);
}
__device__ __forceinline__ float bf2f(unsigned short u) {
    union { unsigned u; float f; } v; v.u = ((unsigned)u) << 16;
    return v.f;
}
__device__ __forceinline__ float elu1(float x) {
    return x > 0.f ? x + 1.f : __expf(x);
}
__device__ __forceinline__ void gload_lds16(const void* g, void* l) {
    __builtin_amdgcn_global_load_lds(
        (const __attribute__((address_space(1))) unsigned int*)g,
        (__attribute__((address_space(3))) unsigned int*)l, 16, 0, 0);
}

#define MFMA16(a, b, c) __builtin_amdgcn_mfma_f32_16x16x32_bf16((a), (b), (c), 0, 0, 0)

// ---------- fp32 -> bf16 convert ----------
__global__ __launch_bounds__(256) void cvt_bf16(
    const float* __restrict__ src, short* __restrict__ dst, int n)
{
    const int i = (blockIdx.x * 256 + threadIdx.x) * 4;
    if (i < n) {
        const float4 v = *(const float4*)(src + i);
        ushort4 o;
        o.x = (unsigned short)f2bf(v.x);
        o.y = (unsigned short)f2bf(v.y);
        o.z = (unsigned short)f2bf(v.z);
        o.w = (unsigned short)f2bf(v.w);
        *(ushort4*)(dst + i) = o;
    }
}

// ---------- GEMM 256x256, BK=64, 2-slot dbuf, counted vmcnt, conflict-free LDS ----------
// C = A(bf16[M][lda]) @ Bt(bf16[Npad][ldb])^T.  grid 1-D (M/256)*(Npad/256), 512 thr.
// K mult of 64, K>=128.  LDS rows = 128B, swizzle byte ^= ((row&7)<<4) via
// pre-permuted global source (linear gload_lds dest) + permuted ds_read.
// EPI: 0=f32 plain, 1=bf16 plain, 2=q-mode (rope+elu+[b,h,s,192]), 3=kv-mode (elu K / V split)
template <int EPI>
__global__ __launch_bounds__(512, 2) void gemm256(
    const short* __restrict__ A, int lda,
    const short* __restrict__ Bt, int ldb,
    void* __restrict__ C0, void* __restrict__ C1, int ldc,
    int Nvalid, int K, int nbx,
    const float* __restrict__ cosT, const float* __restrict__ sinT)
{
    __shared__ char ldsB[131072];   // A slots [0,64K), B slots [64K,128K); slot=32KB
    const int t = threadIdx.x;
    const int lane = t & 63, w = t >> 6;

    // bijective XCD swizzle (grid % 8 == 0 at all call sites)
    const int cpx = gridDim.x >> 3;
    const int id = (blockIdx.x & 7) * cpx + (blockIdx.x >> 3);
    const int row0 = (id % nbx) * 256;
    const int col0 = (id / nbx) * 256;

    // staging: wave w stages rows [w*32, w*32+32); 4 issues of 8 rows x 128B
    const int r8 = lane >> 3;                       // row within issue, 0..7
    const int srcb = (((lane & 7) ^ r8) << 4);      // pre-permuted source byte
    const char* aSrc = (const char*)A + ((size_t)(row0 + w * 32 + r8) * lda) * 2 + srcb;
    const char* bSrc = (const char*)Bt + ((size_t)(col0 + w * 32 + r8) * ldb) * 2 + srcb;
    const size_t aRow8 = (size_t)lda * 16;          // 8 rows in bytes
    const size_t bRow8 = (size_t)ldb * 16;
    char* aDst = ldsB + w * 4096 + lane * 16;
    char* bDst = ldsB + 65536 + w * 4096 + lane * 16;

    // compute: wave grid 2(M)x4(N), per-wave 128x64 out
    const int wr = (w >> 2) * 128, wc = (w & 3) * 64;
    const int l15 = lane & 15;
    const int g16 = (lane >> 4) * 16;
    const int rxor = (l15 & 7) << 4;

    const int NT = K >> 6;

    auto STAGE = [&](int j) {
        const int sb = (j & 1) * 32768;
        const size_t kb = (size_t)j * 128;
#pragma unroll
        for (int p = 0; p < 4; ++p) {
            gload_lds16(aSrc + kb + p * aRow8, aDst + sb + p * 1024);
            gload_lds16(bSrc + kb + p * bRow8, bDst + sb + p * 1024);
        }
    };

    f32x4 acc[8][4];
#pragma unroll
    for (int i = 0; i < 8; ++i)
#pragma unroll
        for (int j = 0; j < 4; ++j) acc[i][j] = (f32x4){0.f, 0.f, 0.f, 0.f};

    STAGE(0); STAGE(1);

#pragma unroll 1
    for (int kt = 0; kt < NT; ++kt) {
        if (kt + 1 < NT) asm volatile("s_waitcnt vmcnt(8)" ::: "memory");
        else             asm volatile("s_waitcnt vmcnt(0)" ::: "memory");
        __builtin_amdgcn_s_barrier();
        __builtin_amdgcn_sched_barrier(0);
        const char* aS = ldsB + (kt & 1) * 32768;
        const char* bS = ldsB + 65536 + (kt & 1) * 32768;
        // ---- half 0 ----
        bf16x8 af[8], bf4[4];
#pragma unroll
        for (int i = 0; i < 8; ++i)
            af[i] = *(const bf16x8*)(aS + (wr + i * 16 + l15) * 128 + (g16 ^ rxor));
#pragma unroll
        for (int j = 0; j < 4; ++j)
            bf4[j] = *(const bf16x8*)(bS + (wc + j * 16 + l15) * 128 + (g16 ^ rxor));
        asm volatile("s_waitcnt lgkmcnt(0)" ::: "memory");
        __builtin_amdgcn_sched_barrier(0);
        __builtin_amdgcn_s_setprio(1);
#pragma unroll
        for (int i = 0; i < 8; ++i)
#pragma unroll
            for (int j = 0; j < 4; ++j)
                acc[i][j] = MFMA16(af[i], bf4[j], acc[i][j]);
        __builtin_amdgcn_s_setprio(0);
        // ---- half 1 ----
#pragma unroll
        for (int i = 0; i < 8; ++i)
            af[i] = *(const bf16x8*)(aS + (wr + i * 16 + l15) * 128 + ((64 + g16) ^ rxor));
#pragma unroll
        for (int j = 0; j < 4; ++j)
            bf4[j] = *(const bf16x8*)(bS + (wc + j * 16 + l15) * 128 + ((64 + g16) ^ rxor));
        asm volatile("s_waitcnt lgkmcnt(0)" ::: "memory");
        __builtin_amdgcn_sched_barrier(0);
        __builtin_amdgcn_s_barrier();
        if (kt + 2 < NT) STAGE(kt + 2);
        __builtin_amdgcn_s_setprio(1);
#pragma unroll
        for (int i = 0; i < 8; ++i)
#pragma unroll
            for (int j = 0; j < 4; ++j)
                acc[i][j] = MFMA16(af[i], bf4[j], acc[i][j]);
        __builtin_amdgcn_s_setprio(0);
    }

    const int rbase = (lane >> 4) * 4;
#pragma unroll
    for (int i = 0; i < 8; ++i)
#pragma unroll
        for (int j = 0; j < 4; ++j) {
            const int cc = col0 + wc + j * 16 + l15;
            if (EPI <= 1) {
                if (cc < Nvalid) {
#pragma unroll
                    for (int q = 0; q < 4; ++q) {
                        const size_t o = (size_t)(row0 + wr + i * 16 + rbase + q) * ldc + cc;
                        if (EPI == 1) ((short*)C0)[o] = f2bf(acc[i][j][q]);
                        else          ((float*)C0)[o] = acc[i][j][q];
                    }
                }
            } else if (EPI == 2) {
                const int hh = cc / 192, d = cc - hh * 192;
#pragma unroll
                for (int q = 0; q < 4; ++q) {
                    const int row = row0 + wr + i * 16 + rbase + q;
                    const int s = row & 4095, b = row >> 12;
                    const float v = acc[i][j][q];
                    const float pv = __shfl_xor(v, 1, 64);
                    float val;
                    if (d >= 128) {
                        const int p = (d - 128) >> 1;
                        const float c = cosT[(size_t)s * 32 + p];
                        const float si = sinT[(size_t)s * 32 + p];
                        val = ((d & 1) == 0) ? (v * c - pv * si) : (pv * si + v * c);
                    } else val = v;
                    ((short*)C0)[((size_t)(b * 16 + hh) * 4096 + s) * 192 + d] = f2bf(elu1(val));
                }
            } else {  // EPI == 3
                const int hh = cc >> 8, d = cc & 255;
#pragma unroll
                for (int q = 0; q < 4; ++q) {
                    const int row = row0 + wr + i * 16 + rbase + q;
                    const int s = row & 4095, b = row >> 12;
                    const float v = acc[i][j][q];
                    if (d < 128)
                        ((short*)C0)[((size_t)(b * 16 + hh) * 4096 + s) * 192 + d] = f2bf(elu1(v));
                    else
                        ((short*)C1)[((size_t)(b * 16 + hh) * 4096 + s) * 128 + d - 128] = f2bf(v);
                }
            }
        }
}

// ---------- RMSNorm (q-lat, kv-lat) + RoPE+ELU on k_pe (bf16 out) ----------
__global__ __launch_bounds__(256) void rms_rope(
    const short* __restrict__ Y1,
    const float* __restrict__ qw, const float* __restrict__ kvw,
    const float* __restrict__ cosT, const float* __restrict__ sinT,
    short* __restrict__ qn, short* __restrict__ kvn, short* __restrict__ kpe)
{
    __shared__ float red[256];
    const int row = blockIdx.x;
    const int s = row & 4095;
    const int t = threadIdx.x;
    const unsigned short* yr = (const unsigned short*)(Y1 + (size_t)row * 1088);

    float v0 = bf2f(yr[t]), v1 = bf2f(yr[t + 256]);
    red[t] = v0 * v0 + v1 * v1;
    __syncthreads();
    for (int off = 128; off > 0; off >>= 1) {
        if (t < off) red[t] += red[t + off];
        __syncthreads();
    }
    float rs = rsqrtf(red[0] / 512.f + 1e-6f);
    __syncthreads();
    qn[(size_t)row * 512 + t]       = f2bf(v0 * rs * qw[t]);
    qn[(size_t)row * 512 + t + 256] = f2bf(v1 * rs * qw[t + 256]);

    float u0 = bf2f(yr[512 + t]), u1 = bf2f(yr[768 + t]);
    red[t] = u0 * u0 + u1 * u1;
    __syncthreads();
    for (int off = 128; off > 0; off >>= 1) {
        if (t < off) red[t] += red[t + off];
        __syncthreads();
    }
    float rs2 = rsqrtf(red[0] / 512.f + 1e-6f);
    kvn[(size_t)row * 512 + t]       = f2bf(u0 * rs2 * kvw[t]);
    kvn[(size_t)row * 512 + t + 256] = f2bf(u1 * rs2 * kvw[t + 256]);

    if (t < 32) {
        float xr = bf2f(yr[1024 + 2 * t]), xi = bf2f(yr[1024 + 2 * t + 1]);
        float cc = cosT[(size_t)s * 32 + t], sn = sinT[(size_t)s * 32 + t];
        kpe[(size_t)row * 64 + 2 * t]     = f2bf(elu1(xr * cc - xi * sn));
        kpe[(size_t)row * 64 + 2 * t + 1] = f2bf(elu1(xr * sn + xi * cc));
    }
}

// ---------- broadcast roped+elu'd k_pe into k_ssa[...,128:192] for all heads ----------
__global__ __launch_bounds__(256) void build_kpe(
    const short* __restrict__ kpe, short* __restrict__ k_ssa)
{
    const int row = blockIdx.x;
    const int s = row & 4095, b = row >> 12;
    const int t = threadIdx.x;
    const short* pe = kpe + (size_t)row * 64;
#pragma unroll
    for (int it = 0; it < 4; ++it) {
        const int idx = t + it * 256;
        const int h = idx >> 6, dd = idx & 63;
        k_ssa[((size_t)(b * 16 + h) * 4096 + s) * 192 + 128 + dd] = pe[dd];
    }
}

// ---------- transpose init_state [bh][dk][dv] -> [bh][dv][dk] ----------
__global__ __launch_bounds__(256) void init_t_kern(
    const float* __restrict__ init, float* __restrict__ initT)
{
    __shared__ float tile[32][33];
    const int bh = blockIdx.y;
    const int tk = blockIdx.x % 6, tv = blockIdx.x / 6;
    const int r0 = threadIdx.x >> 5, c = threadIdx.x & 31;
    const float* src = init + (size_t)bh * 24576;
    float* dst = initT + (size_t)bh * 24576;
#pragma unroll
    for (int p = 0; p < 4; ++p) {
        const int rr = r0 + 8 * p;
        tile[rr][c] = src[(size_t)(tk * 32 + rr) * 128 + tv * 32 + c];
    }
    __syncthreads();
#pragma unroll
    for (int p = 0; p < 4; ++p) {
        const int rr = r0 + 8 * p;
        dst[(size_t)(tv * 32 + rr) * 192 + tk * 32 + c] = tile[c][rr];
    }
}

// ---------- per-chunk kv^T = V^T K, bf16 transposed output [dv][dk] ----------
__global__ __launch_bounds__(256, 3) void ssa_kv(
    const short* __restrict__ k_ssa, const short* __restrict__ v_ssa,
    short* __restrict__ kvcT)
{
    __shared__ short smem[25600];                    // 51200 B
    short (*lkt)[72] = (short(*)[72])smem;           // [192][72]
    short (*lvt)[72] = (short(*)[72])(smem + 192 * 72);  // [128][72]
    short (*outT)[200] = (short(*)[200])smem;        // [128][200] (alias)
    const int c = blockIdx.x, h = blockIdx.y, b = blockIdx.z;
    const int bh = b * 16 + h;
    const short* Kc = k_ssa + ((size_t)bh * 4096 + c * 64) * 192;
    const short* Vc = v_ssa + ((size_t)bh * 4096 + c * 64) * 128;
    const int t = threadIdx.x, lane = t & 63, w = t >> 6;
    const int l15 = lane & 15, kg = (lane >> 4) * 8, rbase = (lane >> 4) * 4;

    for (int i = t; i < 64 * 48; i += 256) {
        const int row = i / 48, c4 = (i % 48) * 4;
        ushort4 kv4 = *(const ushort4*)(Kc + (size_t)row * 192 + c4);
        lkt[c4 + 0][row] = (short)kv4.x;
        lkt[c4 + 1][row] = (short)kv4.y;
        lkt[c4 + 2][row] = (short)kv4.z;
        lkt[c4 + 3][row] = (short)kv4.w;
    }
    for (int i = t; i < 64 * 32; i += 256) {
        const int row = i >> 5, c4 = (i & 31) * 4;
        ushort4 vv = *(const ushort4*)(Vc + (size_t)row * 128 + c4);
        lvt[c4 + 0][row] = (short)vv.x;
        lvt[c4 + 1][row] = (short)vv.y;
        lvt[c4 + 2][row] = (short)vv.z;
        lvt[c4 + 3][row] = (short)vv.w;
    }
    __syncthreads();

    f32x4 acc[2][12];
#pragma unroll
    for (int i = 0; i < 2; ++i)
#pragma unroll
        for (int j = 0; j < 12; ++j) acc[i][j] = (f32x4){0.f, 0.f, 0.f, 0.f};
#pragma unroll
    for (int ks = 0; ks < 2; ++ks) {
        bf16x8 af[2];
#pragma unroll
        for (int i = 0; i < 2; ++i) af[i] = *(const bf16x8*)&lvt[w * 32 + i * 16 + l15][ks * 32 + kg];
#pragma unroll
        for (int j = 0; j < 12; ++j) {
            const bf16x8 bk = *(const bf16x8*)&lkt[j * 16 + l15][ks * 32 + kg];
#pragma unroll
            for (int i = 0; i < 2; ++i) acc[i][j] = MFMA16(af[i], bk, acc[i][j]);
        }
    }
    __syncthreads();
#pragma unroll
    for (int i = 0; i < 2; ++i)
#pragma unroll
        for (int j = 0; j < 12; ++j)
#pragma unroll
            for (int q = 0; q < 4; ++q)
                outT[w * 32 + i * 16 + rbase + q][j * 16 + l15] = f2bf(acc[i][j][q]);
    __syncthreads();

    short* kvp = kvcT + ((size_t)bh * 64 + c) * 24576;
    for (int i = t; i < 3072; i += 256) {
        const int s8 = i * 8;
        const int row = s8 / 192, col = s8 % 192;
        *(u16x8*)(kvp + s8) = *(const u16x8*)&outT[row][col];
    }
}

// ---------- exclusive cumsum over chunks (bf16 in-place) + initT ----------
__global__ __launch_bounds__(256) void ssa_scan(
    short* __restrict__ kvc, const float* __restrict__ initT)
{
    const int bh = blockIdx.y;
    const int e8 = (blockIdx.x * 256 + threadIdx.x) * 8;
    float st[8];
    {
        const float4 i0 = *(const float4*)(initT + (size_t)bh * 24576 + e8);
        const float4 i1 = *(const float4*)(initT + (size_t)bh * 24576 + e8 + 4);
        st[0] = i0.x; st[1] = i0.y; st[2] = i0.z; st[3] = i0.w;
        st[4] = i1.x; st[5] = i1.y; st[6] = i1.z; st[7] = i1.w;
    }
    short* p = kvc + (size_t)bh * 64 * 24576 + e8;
    for (int cc = 0; cc < 64; ++cc) {
        const u16x8 v = *(const u16x8*)p;
        u16x8 o;
#pragma unroll
        for (int j = 0; j < 8; ++j) o[j] = (unsigned short)f2bf(st[j]);
        *(u16x8*)p = o;
#pragma unroll
        for (int j = 0; j < 8; ++j) st[j] += bf2f(v[j]);
        p += 24576;
    }
}

// ---------- fused: sc=tril(QK^T); attn=(sc@V + Q@state)*SCALE ----------
__global__ __launch_bounds__(256, 2) void ssa_out(
    const short* __restrict__ q_ssa, const short* __restrict__ k_ssa,
    const short* __restrict__ v_ssa, const short* __restrict__ states,
    short* __restrict__ attnb)
{
    __shared__ short lk[64][200];
    __shared__ short lvt[128][72];
    __shared__ short lst[128][104];
    __shared__ short lsc[64][72];
    const int c = blockIdx.x, h = blockIdx.y, b = blockIdx.z;
    const int bh = b * 16 + h;
    const short* Qb = q_ssa + ((size_t)bh * 4096 + c * 64) * 192;
    const short* Kc = k_ssa + ((size_t)bh * 4096 + c * 64) * 192;
    const short* Vc = v_ssa + ((size_t)bh * 4096 + c * 64) * 128;
    const short* st = states + ((size_t)bh * 64 + c) * 24576;
    const int t = threadIdx.x, lane = t & 63, w = t >> 6;
    const int l15 = lane & 15, kg = (lane >> 4) * 8, rbase = (lane >> 4) * 4;

    bf16x8 aq[6];
    {
        const short* Qr = Qb + (size_t)(w * 16 + l15) * 192 + kg;
#pragma unroll
        for (int ks = 0; ks < 6; ++ks) aq[ks] = *(const bf16x8*)(Qr + ks * 32);
    }
    for (int i = t; i < 1536; i += 256) {
        const int row = i / 24, c8 = (i % 24) * 8;
        *(u16x8*)&lk[row][c8] = *(const u16x8*)(Kc + (size_t)row * 192 + c8);
    }
    for (int i = t; i < 2048; i += 256) {
        const int row = i >> 5, c4 = (i & 31) * 4;
        ushort4 vv = *(const ushort4*)(Vc + (size_t)row * 128 + c4);
        lvt[c4 + 0][row] = (short)vv.x;
        lvt[c4 + 1][row] = (short)vv.y;
        lvt[c4 + 2][row] = (short)vv.z;
        lvt[c4 + 3][row] = (short)vv.w;
    }
    for (int i = t; i < 1536; i += 256) {
        const int row = i / 12, c8 = (i % 12) * 8;
        *(u16x8*)&lst[row][c8] = *(const u16x8*)(st + (size_t)row * 192 + c8);
    }
    __syncthreads();

    {
        f32x4 sc[4];
#pragma unroll
        for (int j = 0; j < 4; ++j) sc[j] = (f32x4){0.f, 0.f, 0.f, 0.f};
#pragma unroll
        for (int ks = 0; ks < 6; ++ks)
#pragma unroll
            for (int j = 0; j < 4; ++j) {
                const bf16x8 bk = *(const bf16x8*)&lk[j * 16 + l15][ks * 32 + kg];
                sc[j] = MFMA16(aq[ks], bk, sc[j]);
            }
#pragma unroll
        for (int j = 0; j < 4; ++j)
#pragma unroll
            for (int q = 0; q < 4; ++q) {
                const int l = w * 16 + rbase + q;
                const int m = j * 16 + l15;
                lsc[l][m] = f2bf((m <= l) ? sc[j][q] : 0.f);
            }
    }
    __syncthreads();

    f32x4 acc[8];
#pragma unroll
    for (int j = 0; j < 8; ++j) acc[j] = (f32x4){0.f, 0.f, 0.f, 0.f};
#pragma unroll
    for (int ks = 0; ks < 2; ++ks) {
        const bf16x8 as = *(const bf16x8*)&lsc[w * 16 + l15][ks * 32 + kg];
#pragma unroll
        for (int j = 0; j < 8; ++j) {
            const bf16x8 bv = *(const bf16x8*)&lvt[j * 16 + l15][ks * 32 + kg];
            acc[j] = MFMA16(as, bv, acc[j]);
        }
    }
#pragma unroll
    for (int ks = 0; ks < 3; ++ks)
#pragma unroll
        for (int j = 0; j < 8; ++j) {
            const bf16x8 bs = *(const bf16x8*)&lst[j * 16 + l15][ks * 32 + kg];
            acc[j] = MFMA16(aq[ks], bs, acc[j]);
        }
    __syncthreads();
    for (int i = t; i < 1536; i += 256) {
        const int row = i / 12, c8 = (i % 12) * 8;
        *(u16x8*)&lst[row][c8] = *(const u16x8*)(st + (size_t)row * 192 + 96 + c8);
    }
    __syncthreads();
#pragma unroll
    for (int ks = 3; ks < 6; ++ks)
#pragma unroll
        for (int j = 0; j < 8; ++j) {
            const bf16x8 bs = *(const bf16x8*)&lst[j * 16 + l15][(ks - 3) * 32 + kg];
            acc[j] = MFMA16(aq[ks], bs, acc[j]);
        }

    const float scale = 0.07216878364870322f;  // 192^-0.5
#pragma unroll
    for (int j = 0; j < 8; ++j)
#pragma unroll
        for (int q = 0; q < 4; ++q) {
            const int l = w * 16 + rbase + q;
            const int dv = j * 16 + l15;
            attnb[((size_t)(b * 4096 + c * 64 + l)) * 2048 + h * 128 + dv] = f2bf(acc[j][q] * scale);
        }
}

// ---------- launch ----------
extern "C" void kernel_launch(void* const* d_in, const int* in_sizes, int n_in,
                              void* d_out, int out_size, void* d_ws, size_t ws_size,
                              hipStream_t stream) {
    const float* x     = (const float*)d_in[0];
    const float* cosT  = (const float*)d_in[2];
    const float* sinT  = (const float*)d_in[3];
    const float* wq_a  = (const float*)d_in[4];
    const float* wq_b  = (const float*)d_in[5];
    const float* wkv_a = (const float*)d_in[6];
    const float* wkv_b = (const float*)d_in[7];
    const float* wo    = (const float*)d_in[8];
    const float* qw    = (const float*)d_in[9];
    const float* kvw   = (const float*)d_in[10];
    const float* init  = (const float*)d_in[11];
    float* out = (float*)d_out;

    void* base = nullptr;
    hipGetSymbolAddress(&base, HIP_SYMBOL(g_ws));
    char* ws = (char*)base;
    size_t off = 0;
    auto take = [&](size_t bytes) -> char* {
        char* p = ws + off;
        off += (bytes + 255) & ~(size_t)255;
        return p;
    };
    short* xb    = (short*)take((size_t)8192 * 2048 * 2);
    short* wab   = (short*)take((size_t)1280 * 2048 * 2);   // [wq_a;wkv_a;pad to 1280]
    short* wqbb  = (short*)take((size_t)3072 * 512 * 2);
    short* wkvbb = (short*)take((size_t)4096 * 512 * 2);
    short* wob   = (short*)take((size_t)2048 * 2048 * 2);
    short* y1b   = (short*)take((size_t)8192 * 1088 * 2);
    short* qnb   = (short*)take((size_t)8192 * 512 * 2);
    short* kvnb  = (short*)take((size_t)8192 * 512 * 2);
    short* kpe   = (short*)take((size_t)8192 * 64 * 2);
    short* qs    = (short*)take((size_t)2 * 16 * 4096 * 192 * 2);
    short* ksb   = (short*)take((size_t)2 * 16 * 4096 * 192 * 2);
    short* vsb   = (short*)take((size_t)2 * 16 * 4096 * 128 * 2);
    short* kvcT  = (short*)take((size_t)2048 * 24576 * 2);
    float* initT = (float*)take((size_t)32 * 24576 * 4);
    short* attnb = (short*)take((size_t)8192 * 2048 * 2);

    // 0. convert inputs/weights to bf16; transpose init
    cvt_bf16<<<(8192 * 2048 / 4 + 255) / 256, 256, 0, stream>>>(x, xb, 8192 * 2048);
    cvt_bf16<<<(512 * 2048 / 4 + 255) / 256, 256, 0, stream>>>(wq_a, wab, 512 * 2048);
    cvt_bf16<<<(576 * 2048 / 4 + 255) / 256, 256, 0, stream>>>(wkv_a, wab + (size_t)512 * 2048, 576 * 2048);
    hipMemsetAsync(wab + (size_t)1088 * 2048, 0, (size_t)192 * 2048 * 2, stream);
    cvt_bf16<<<(3072 * 512 / 4 + 255) / 256, 256, 0, stream>>>(wq_b, wqbb, 3072 * 512);
    cvt_bf16<<<(4096 * 512 / 4 + 255) / 256, 256, 0, stream>>>(wkv_b, wkvbb, 4096 * 512);
    cvt_bf16<<<(2048 * 2048 / 4 + 255) / 256, 256, 0, stream>>>(wo, wob, 2048 * 2048);
    init_t_kern<<<dim3(24, 32), 256, 0, stream>>>(init, initT);

    // 1. Y1 = x @ [wq_a; wkv_a]^T   (Npad=1280, Nvalid=1088)
    gemm256<1><<<160, 512, 0, stream>>>(xb, 2048, wab, 2048, y1b, nullptr, 1088, 1088, 2048, 32, nullptr, nullptr);
    // 2. RMSNorm + rope(k_pe)+elu
    rms_rope<<<8192, 256, 0, stream>>>(y1b, qw, kvw, cosT, sinT, qnb, kvnb, kpe);
    // 3a. q = qn @ wq_b^T  -> fused rope+elu+relayout into qs
    gemm256<2><<<384, 512, 0, stream>>>(qnb, 512, wqbb, 512, qs, nullptr, 0, 3072, 512, 32, cosT, sinT);
    // 3b. kv = kvn @ wkv_b^T -> fused elu K / V split
    gemm256<3><<<512, 512, 0, stream>>>(kvnb, 512, wkvbb, 512, ksb, vsb, 0, 4096, 512, 32, nullptr, nullptr);
    build_kpe<<<8192, 256, 0, stream>>>(kpe, ksb);
    // 4. SSA
    ssa_kv<<<dim3(64, 16, 2), 256, 0, stream>>>(ksb, vsb, kvcT);
    ssa_scan<<<dim3(12, 32), 256, 0, stream>>>(kvcT, initT);
    ssa_out<<<dim3(64, 16, 2), 256, 0, stream>>>(qs, ksb, vsb, kvcT, attnb);
    // 5. out = attn @ wo^T (fp32 out)
    gemm256<0><<<256, 512, 0, stream>>>(attnb, 2048, wob, 2048, out, nullptr, 2048, 2048, 2048, 32, nullptr, nullptr);
}